// Round 1
// baseline (3376.746 us; speedup 1.0000x reference)
//
#include <hip/hip_runtime.h>
#include <cstdint>
#include <math.h>

// GPT-2 forward, MI355X. B=2, T=1024, D=1024, NH=16, HD=64, L=12, F=4096, V=50257.
// fp32 residual stream; bf16 MFMA GEMMs (m97 structure); flash attention with
// XOR-swizzled LDS tiles; fp32 final LN + lm_head.

using u16 = unsigned short;
using bf16x8 = __attribute__((ext_vector_type(8))) short;
using f32x4 = __attribute__((ext_vector_type(4))) float;

#define GLDS16(g, l)                                                        \
  __builtin_amdgcn_global_load_lds(                                         \
      (const __attribute__((address_space(1))) void*)(g),                   \
      (__attribute__((address_space(3))) void*)(l), 16, 0, 0)

__device__ __forceinline__ u16 f2bf(float f) {
  union { float f; unsigned u; } t; t.f = f;
  unsigned r = t.u + 0x7fffu + ((t.u >> 16) & 1u);
  return (u16)(r >> 16);
}

#define DD 1024
#define NHD 16
#define HDD 64
#define TTT 1024
#define MR 2048     // B*T
#define FFF 4096
#define VVV 50257

// ---------------- embedding ----------------
__global__ __launch_bounds__(256) void k_embed(const int* __restrict__ tokens,
                                               const float* __restrict__ wte,
                                               const float* __restrict__ wpe,
                                               float* __restrict__ x) {
  int m = blockIdx.x, d = threadIdx.x * 4;
  int t = m & (TTT - 1);
  int tok = tokens[m];
  const float4 a = *(const float4*)(wte + (size_t)tok * DD + d);
  const float4 p = *(const float4*)(wpe + (size_t)t * DD + d);
  float4 o; o.x = a.x + p.x; o.y = a.y + p.y; o.z = a.z + p.z; o.w = a.w + p.w;
  *(float4*)(x + (size_t)m * DD + d) = o;
}

// ---------------- layernorm -> bf16 ----------------
__global__ __launch_bounds__(256) void k_ln(const float* __restrict__ x,
                                            const float* __restrict__ w,
                                            const float* __restrict__ b,
                                            u16* __restrict__ out) {
  int m = blockIdx.x, tid = threadIdx.x;
  const float4 v = *(const float4*)(x + (size_t)m * DD + tid * 4);
  float s = v.x + v.y + v.z + v.w;
  float q = v.x * v.x + v.y * v.y + v.z * v.z + v.w * v.w;
#pragma unroll
  for (int off = 1; off < 64; off <<= 1) { s += __shfl_xor(s, off); q += __shfl_xor(q, off); }
  __shared__ float sm[8];
  int wid = tid >> 6;
  if ((tid & 63) == 0) { sm[wid] = s; sm[4 + wid] = q; }
  __syncthreads();
  s = sm[0] + sm[1] + sm[2] + sm[3];
  q = sm[4] + sm[5] + sm[6] + sm[7];
  float mean = s * (1.f / DD);
  float var = q * (1.f / DD) - mean * mean;
  float rs = rsqrtf(var + 1e-5f);
  const float4 wv = *(const float4*)(w + tid * 4);
  const float4 bv = *(const float4*)(b + tid * 4);
  u16 o[4];
  o[0] = f2bf((v.x - mean) * rs * wv.x + bv.x);
  o[1] = f2bf((v.y - mean) * rs * wv.y + bv.y);
  o[2] = f2bf((v.z - mean) * rs * wv.z + bv.z);
  o[3] = f2bf((v.w - mean) * rs * wv.w + bv.w);
  *(uint64_t*)(out + (size_t)m * DD + tid * 4) = *(uint64_t*)o;
}

// final LN on the two last-token rows, fp32 out
__global__ __launch_bounds__(256) void k_lnf(const float* __restrict__ x,
                                             const float* __restrict__ w,
                                             const float* __restrict__ b,
                                             float* __restrict__ out) {
  int bb = blockIdx.x, tid = threadIdx.x;
  int m = bb * TTT + (TTT - 1);
  const float4 v = *(const float4*)(x + (size_t)m * DD + tid * 4);
  float s = v.x + v.y + v.z + v.w;
  float q = v.x * v.x + v.y * v.y + v.z * v.z + v.w * v.w;
#pragma unroll
  for (int off = 1; off < 64; off <<= 1) { s += __shfl_xor(s, off); q += __shfl_xor(q, off); }
  __shared__ float sm[8];
  int wid = tid >> 6;
  if ((tid & 63) == 0) { sm[wid] = s; sm[4 + wid] = q; }
  __syncthreads();
  s = sm[0] + sm[1] + sm[2] + sm[3];
  q = sm[4] + sm[5] + sm[6] + sm[7];
  float mean = s * (1.f / DD);
  float var = q * (1.f / DD) - mean * mean;
  float rs = rsqrtf(var + 1e-5f);
  const float4 wv = *(const float4*)(w + tid * 4);
  const float4 bv = *(const float4*)(b + tid * 4);
  float4 o;
  o.x = (v.x - mean) * rs * wv.x + bv.x;
  o.y = (v.y - mean) * rs * wv.y + bv.y;
  o.z = (v.z - mean) * rs * wv.z + bv.z;
  o.w = (v.w - mean) * rs * wv.w + bv.w;
  *(float4*)(out + (size_t)bb * DD + tid * 4) = o;
}

// ---------------- weight transpose fp32[K,N] -> bf16[N,K] ----------------
__global__ __launch_bounds__(256) void k_wtrans(const float* __restrict__ W,
                                                u16* __restrict__ Wt, int K, int N) {
  __shared__ float tile[32][33];
  int k0 = blockIdx.x * 32, n0 = blockIdx.y * 32;
  int tx = threadIdx.x & 31, ty = threadIdx.x >> 5;  // ty in [0,8)
#pragma unroll
  for (int i = 0; i < 4; ++i)
    tile[ty + i * 8][tx] = W[(size_t)(k0 + ty + i * 8) * N + n0 + tx];
  __syncthreads();
#pragma unroll
  for (int i = 0; i < 4; ++i)
    Wt[(size_t)(n0 + ty + i * 8) * K + k0 + tx] = f2bf(tile[tx][ty + i * 8]);
}

// ---------------- GEMM: out = A[M,K] * Bt[N,K]^T + bias, m97 structure ----------------
// EPI 0: bf16 out; EPI 1: xres += (fp32 residual); EPI 2: gelu -> bf16 out
template <int EPI>
__global__ __launch_bounds__(256) void k_gemm(const u16* __restrict__ A,
                                              const u16* __restrict__ Bt,
                                              const float* __restrict__ bias,
                                              u16* __restrict__ outb,
                                              float* __restrict__ xres,
                                              int M, int N, int K) {
  __shared__ u16 As[128 * 64];
  __shared__ u16 Bs[128 * 64];
  const int tid = threadIdx.x;
  const int lane = tid & 63, wid = tid >> 6;
  const int wr = wid >> 1, wc = wid & 1;
  const int l15 = lane & 15, l4 = lane >> 4;
  const int m0 = blockIdx.x * 128, n0 = blockIdx.y * 128;
  f32x4 acc[4][4] = {};

  const int srow = tid >> 3, scol = (tid & 7) * 8;
  for (int k0 = 0; k0 < K; k0 += 64) {
#pragma unroll
    for (int it = 0; it < 4; ++it) {
      GLDS16(A + (size_t)(m0 + srow + it * 32) * K + k0 + scol, (char*)As + it * 4096 + tid * 16);
      GLDS16(Bt + (size_t)(n0 + srow + it * 32) * K + k0 + scol, (char*)Bs + it * 4096 + tid * 16);
    }
    __syncthreads();
#pragma unroll
    for (int ks = 0; ks < 2; ++ks) {
      bf16x8 af[4], bfr[4];
#pragma unroll
      for (int i = 0; i < 4; ++i)
        af[i] = *(const bf16x8*)(As + (wr * 64 + i * 16 + l15) * 64 + ks * 32 + l4 * 8);
#pragma unroll
      for (int j = 0; j < 4; ++j)
        bfr[j] = *(const bf16x8*)(Bs + (wc * 64 + j * 16 + l15) * 64 + ks * 32 + l4 * 8);
#pragma unroll
      for (int i = 0; i < 4; ++i)
#pragma unroll
        for (int j = 0; j < 4; ++j)
          acc[i][j] = __builtin_amdgcn_mfma_f32_16x16x32_bf16(af[i], bfr[j], acc[i][j], 0, 0, 0);
    }
    __syncthreads();
  }
#pragma unroll
  for (int j = 0; j < 4; ++j) {
    const int col = n0 + wc * 64 + j * 16 + l15;
    const float bs = bias[col];
#pragma unroll
    for (int i = 0; i < 4; ++i) {
#pragma unroll
      for (int r = 0; r < 4; ++r) {
        const int row = m0 + wr * 64 + i * 16 + l4 * 4 + r;
        float v = acc[i][j][r] + bs;
        if (EPI == 0) {
          outb[(size_t)row * N + col] = f2bf(v);
        } else if (EPI == 1) {
          xres[(size_t)row * N + col] += v;
        } else {
          float g = 0.5f * v * (1.f + erff(v * 0.70710678118f));
          outb[(size_t)row * N + col] = f2bf(g);
        }
      }
    }
  }
}

// ---------------- qkv repack: head n = d%16, h = d/16 ----------------
__global__ __launch_bounds__(256) void k_repack(const u16* __restrict__ qkv,
                                                u16* __restrict__ Qb,
                                                u16* __restrict__ Kb,
                                                u16* __restrict__ Vt) {
  int m = blockIdx.x;
  int c = blockIdx.y * 256 + threadIdx.x;
  int b = m >> 10, t = m & 1023;
  u16 v = qkv[(size_t)m * 3072 + c];
  int part = c >> 10, d = c & 1023;
  int n = d & 15, h = d >> 4;
  size_t bn = (size_t)b * NHD + n;
  if (part == 0)      Qb[(bn * TTT + t) * HDD + h] = v;
  else if (part == 1) Kb[(bn * TTT + t) * HDD + h] = v;
  else                Vt[(bn * HDD + h) * TTT + t] = v;
}

// ---------------- flash attention (causal), 64-row Q tiles ----------------
__global__ __launch_bounds__(256) void k_attn(const u16* __restrict__ Qb,
                                              const u16* __restrict__ Kb,
                                              const u16* __restrict__ Vt,
                                              u16* __restrict__ attout) {
  __shared__ u16 Qs[64 * 64];
  __shared__ u16 Ks[64 * 64];
  __shared__ u16 Vs[64 * 64];   // [h][key]
  __shared__ u16 Ps[4][16 * 72];

  const int tid = threadIdx.x;
  const int lane = tid & 63, wid = tid >> 6;
  const int l15 = lane & 15, l4 = lane >> 4;
  const int bn = blockIdx.x;          // b*16 + n
  const int q0 = blockIdx.y * 64;
  const int b = bn >> 4, nh = bn & 15;

  const char* Qg = (const char*)(Qb + ((size_t)bn * TTT + q0) * HDD);
  const char* Kg0 = (const char*)(Kb + (size_t)bn * TTT * HDD);
  const char* Vg0 = (const char*)(Vt + (size_t)bn * HDD * TTT);

  // stage Q tile: linear LDS dest, XOR-swizzled global source (rule #21)
#pragma unroll
  for (int it = 0; it < 2; ++it) {
    int L = it * 4096 + tid * 16;
    int Ls = L ^ (((L >> 7) & 7) << 4);
    GLDS16(Qg + Ls, (char*)Qs + L);
  }

  float m_run[4], l_run[4];
  f32x4 o[4] = {};  // o[hf][r]: O[q=l4*4+r][h=hf*16+l15]
#pragma unroll
  for (int r = 0; r < 4; ++r) { m_run[r] = -1e30f; l_run[r] = 0.f; }

  const int ntk = blockIdx.y + 1;
  for (int kt = 0; kt < ntk; ++kt) {
    const char* Kg = Kg0 + (size_t)kt * 8192;
#pragma unroll
    for (int it = 0; it < 2; ++it) {
      int L = it * 4096 + tid * 16;
      int Ls = L ^ (((L >> 7) & 7) << 4);
      GLDS16(Kg + Ls, (char*)Ks + L);
    }
#pragma unroll
    for (int it = 0; it < 2; ++it) {
      int L = it * 4096 + tid * 16;
      int Ls = L ^ (((L >> 7) & 7) << 4);
      int hrow = Ls >> 7, cb = Ls & 127;
      GLDS16(Vg0 + (size_t)hrow * 2048 + kt * 128 + cb, (char*)Vs + L);
    }
    __syncthreads();

    // Q A-frags (rows = q within wave's 16)
    bf16x8 aq[2];
#pragma unroll
    for (int ks = 0; ks < 2; ++ks) {
      int P = (wid * 16 + l15) * 128 + (ks * 32 + l4 * 8) * 2;
      aq[ks] = *(const bf16x8*)((const char*)Qs + (P ^ (((P >> 7) & 7) << 4)));
    }
    // S = Q K^T
    f32x4 sf[4];
#pragma unroll
    for (int cf = 0; cf < 4; ++cf) {
      f32x4 z = {};
#pragma unroll
      for (int ks = 0; ks < 2; ++ks) {
        int P = (cf * 16 + l15) * 128 + (ks * 32 + l4 * 8) * 2;
        bf16x8 kb = *(const bf16x8*)((const char*)Ks + (P ^ (((P >> 7) & 7) << 4)));
        z = __builtin_amdgcn_mfma_f32_16x16x32_bf16(aq[ks], kb, z, 0, 0, 0);
      }
      sf[cf] = z;
    }
    // scale + causal mask (diagonal tile only)
#pragma unroll
    for (int cf = 0; cf < 4; ++cf)
#pragma unroll
      for (int r = 0; r < 4; ++r) {
        float s = sf[cf][r] * 0.125f;
        if (kt == ntk - 1) {
          int kg = kt * 64 + cf * 16 + l15;
          int qg = q0 + wid * 16 + l4 * 4 + r;
          if (kg > qg) s = -1e30f;
        }
        sf[cf][r] = s;
      }
    // online softmax per row r
    float fac[4];
#pragma unroll
    for (int r = 0; r < 4; ++r) {
      float tm = fmaxf(fmaxf(sf[0][r], sf[1][r]), fmaxf(sf[2][r], sf[3][r]));
#pragma unroll
      for (int off = 1; off < 16; off <<= 1) tm = fmaxf(tm, __shfl_xor(tm, off));
      float mnew = fmaxf(m_run[r], tm);
      fac[r] = __expf(m_run[r] - mnew);
      m_run[r] = mnew;
      float ts = 0.f;
#pragma unroll
      for (int cf = 0; cf < 4; ++cf) {
        float p = __expf(sf[cf][r] - mnew);
        sf[cf][r] = p;
        ts += p;
      }
#pragma unroll
      for (int off = 1; off < 16; off <<= 1) ts += __shfl_xor(ts, off);
      l_run[r] = l_run[r] * fac[r] + ts;
    }
    // P -> LDS (bf16), per-wave region
#pragma unroll
    for (int cf = 0; cf < 4; ++cf)
#pragma unroll
      for (int r = 0; r < 4; ++r)
        Ps[wid][(l4 * 4 + r) * 72 + cf * 16 + l15] = f2bf(sf[cf][r]);
    // rescale O
#pragma unroll
    for (int hf = 0; hf < 4; ++hf)
#pragma unroll
      for (int r = 0; r < 4; ++r) o[hf][r] *= fac[r];
    // PV
    bf16x8 pa[2];
#pragma unroll
    for (int ks = 0; ks < 2; ++ks)
      pa[ks] = *(const bf16x8*)&Ps[wid][l15 * 72 + ks * 32 + l4 * 8];
#pragma unroll
    for (int hf = 0; hf < 4; ++hf) {
#pragma unroll
      for (int ks = 0; ks < 2; ++ks) {
        int P = (hf * 16 + l15) * 128 + (ks * 32 + l4 * 8) * 2;
        bf16x8 vb = *(const bf16x8*)((const char*)Vs + (P ^ (((P >> 7) & 7) << 4)));
        o[hf] = __builtin_amdgcn_mfma_f32_16x16x32_bf16(pa[ks], vb, o[hf], 0, 0, 0);
      }
    }
    __syncthreads();
  }
  // write att out: d = nh*64 + h (reference's output concat layout)
#pragma unroll
  for (int hf = 0; hf < 4; ++hf)
#pragma unroll
    for (int r = 0; r < 4; ++r) {
      float val = o[hf][r] / l_run[r];
      size_t row = (size_t)b * TTT + q0 + wid * 16 + l4 * 4 + r;
      attout[row * DD + nh * 64 + hf * 16 + l15] = f2bf(val);
    }
}

// ---------------- lm head: out[b][v] = dot(xlnf[b], wte[v]) fp32 ----------------
__global__ __launch_bounds__(256) void k_head(const float* __restrict__ xlnf,
                                              const float* __restrict__ wte,
                                              float* __restrict__ out) {
  __shared__ float xs[2 * DD];
  int tid = threadIdx.x;
#pragma unroll
  for (int i = 0; i < 2; ++i)
    *(float4*)(xs + i * DD + tid * 4) = *(const float4*)(xlnf + i * DD + tid * 4);
  __syncthreads();
  int wid = tid >> 6, lane = tid & 63;
  for (int v = blockIdx.x * 4 + wid; v < VVV; v += gridDim.x * 4) {
    const float* wr = wte + (size_t)v * DD;
    float a0 = 0.f, a1 = 0.f;
#pragma unroll
    for (int j = 0; j < 4; ++j) {
      const float4 wv = *(const float4*)(wr + lane * 16 + j * 4);
      const float4 x0 = *(const float4*)(xs + lane * 16 + j * 4);
      const float4 x1 = *(const float4*)(xs + DD + lane * 16 + j * 4);
      a0 += wv.x * x0.x + wv.y * x0.y + wv.z * x0.z + wv.w * x0.w;
      a1 += wv.x * x1.x + wv.y * x1.y + wv.z * x1.z + wv.w * x1.w;
    }
#pragma unroll
    for (int off = 1; off < 64; off <<= 1) { a0 += __shfl_xor(a0, off); a1 += __shfl_xor(a1, off); }
    if (lane == 0) { out[v] = a0; out[VVV + v] = a1; }
  }
}

extern "C" void kernel_launch(void* const* d_in, const int* in_sizes, int n_in,
                              void* d_out, int out_size, void* d_ws, size_t ws_size,
                              hipStream_t stream) {
  const int* tokens    = (const int*)d_in[0];
  const float* wte     = (const float*)d_in[1];
  const float* wpe     = (const float*)d_in[2];
  const float* ln1_w   = (const float*)d_in[3];
  const float* ln1_b   = (const float*)d_in[4];
  const float* attn_w  = (const float*)d_in[5];
  const float* attn_b  = (const float*)d_in[6];
  const float* aproj_w = (const float*)d_in[7];
  const float* aproj_b = (const float*)d_in[8];
  const float* ln2_w   = (const float*)d_in[9];
  const float* ln2_b   = (const float*)d_in[10];
  const float* fc_w    = (const float*)d_in[11];
  const float* fc_b    = (const float*)d_in[12];
  const float* proj_w  = (const float*)d_in[13];
  const float* proj_b  = (const float*)d_in[14];
  const float* lnf_w   = (const float*)d_in[15];
  const float* lnf_b   = (const float*)d_in[16];

  char* ws = (char*)d_ws;
  float* x   = (float*)(ws);                    // 8 MB
  u16* h     = (u16*)(ws + (8u << 20));         // 4 MB
  u16* qkv   = (u16*)(ws + (12u << 20));        // 12 MB
  u16* Qb    = (u16*)(ws + (24u << 20));        // 4 MB
  u16* Kb    = (u16*)(ws + (28u << 20));        // 4 MB
  u16* Vt    = (u16*)(ws + (32u << 20));        // 4 MB
  u16* attb  = (u16*)(ws + (36u << 20));        // 4 MB
  u16* mlph  = (u16*)(ws + (40u << 20));        // 16 MB
  u16* wt    = (u16*)(ws + (56u << 20));        // 8 MB
  float* xlnf = (float*)(ws + (64u << 20));     // 8 KB
  float* out = (float*)d_out;

  k_embed<<<MR, 256, 0, stream>>>(tokens, wte, wpe, x);

  for (int l = 0; l < 12; ++l) {
    k_ln<<<MR, 256, 0, stream>>>(x, ln1_w + l * DD, ln1_b + l * DD, h);
    k_wtrans<<<dim3(32, 96), 256, 0, stream>>>(attn_w + (size_t)l * DD * 3 * DD, wt, 1024, 3072);
    k_gemm<0><<<dim3(16, 24), 256, 0, stream>>>(h, wt, attn_b + (size_t)l * 3 * DD, qkv, nullptr, MR, 3072, 1024);
    k_repack<<<dim3(MR, 12), 256, 0, stream>>>(qkv, Qb, Kb, Vt);
    k_attn<<<dim3(32, 16), 256, 0, stream>>>(Qb, Kb, Vt, attb);
    k_wtrans<<<dim3(32, 32), 256, 0, stream>>>(aproj_w + (size_t)l * DD * DD, wt, 1024, 1024);
    k_gemm<1><<<dim3(16, 8), 256, 0, stream>>>(attb, wt, aproj_b + (size_t)l * DD, nullptr, x, MR, 1024, 1024);
    k_ln<<<MR, 256, 0, stream>>>(x, ln2_w + l * DD, ln2_b + l * DD, h);
    k_wtrans<<<dim3(32, 128), 256, 0, stream>>>(fc_w + (size_t)l * DD * FFF, wt, 1024, 4096);
    k_gemm<2><<<dim3(16, 32), 256, 0, stream>>>(h, wt, fc_b + (size_t)l * FFF, mlph, nullptr, MR, 4096, 1024);
    k_wtrans<<<dim3(128, 32), 256, 0, stream>>>(proj_w + (size_t)l * FFF * DD, wt, 4096, 1024);
    k_gemm<1><<<dim3(16, 8), 256, 0, stream>>>(mlph, wt, proj_b + (size_t)l * DD, nullptr, x, MR, 1024, 4096);
  }
  k_lnf<<<2, 256, 0, stream>>>(x, lnf_w, lnf_b, xlnf);
  k_head<<<512, 256, 0, stream>>>(xlnf, wte, out);
}

// Round 2
// 2562.924 us; speedup vs baseline: 1.3175x; 1.3175x over previous
//
#include <hip/hip_runtime.h>
#include <cstdint>
#include <math.h>

// GPT-2 forward, MI355X. B=2, T=1024, D=1024, NH=16, HD=64, L=12, F=4096, V=50257.
// fp32 residual; bf16 MFMA GEMMs (m97 structure + XCD swizzle + split-K for proj);
// flash attention with 128-key tiles, deferred l-sum; LDS de-interleave repack.

using u16 = unsigned short;
using bf16x8 = __attribute__((ext_vector_type(8))) short;
using f32x4 = __attribute__((ext_vector_type(4))) float;

#define GLDS16(g, l)                                                        \
  __builtin_amdgcn_global_load_lds(                                         \
      (const __attribute__((address_space(1))) void*)(g),                   \
      (__attribute__((address_space(3))) void*)(l), 16, 0, 0)

__device__ __forceinline__ u16 f2bf(float f) {
  union { float f; unsigned u; } t; t.f = f;
  unsigned r = t.u + 0x7fffu + ((t.u >> 16) & 1u);
  return (u16)(r >> 16);
}

#define DD 1024
#define TTT 1024
#define MR 2048     // B*T
#define FFF 4096
#define VVV 50257

// ---------------- embedding ----------------
__global__ __launch_bounds__(256) void k_embed(const int* __restrict__ tokens,
                                               const float* __restrict__ wte,
                                               const float* __restrict__ wpe,
                                               float* __restrict__ x) {
  int m = blockIdx.x, d = threadIdx.x * 4;
  int t = m & (TTT - 1);
  int tok = tokens[m];
  const float4 a = *(const float4*)(wte + (size_t)tok * DD + d);
  const float4 p = *(const float4*)(wpe + (size_t)t * DD + d);
  float4 o; o.x = a.x + p.x; o.y = a.y + p.y; o.z = a.z + p.z; o.w = a.w + p.w;
  *(float4*)(x + (size_t)m * DD + d) = o;
}

// ---------------- layernorm -> bf16 ----------------
__global__ __launch_bounds__(256) void k_ln(const float* __restrict__ x,
                                            const float* __restrict__ w,
                                            const float* __restrict__ b,
                                            u16* __restrict__ out) {
  int m = blockIdx.x, tid = threadIdx.x;
  const float4 v = *(const float4*)(x + (size_t)m * DD + tid * 4);
  float s = v.x + v.y + v.z + v.w;
  float q = v.x * v.x + v.y * v.y + v.z * v.z + v.w * v.w;
#pragma unroll
  for (int off = 1; off < 64; off <<= 1) { s += __shfl_xor(s, off); q += __shfl_xor(q, off); }
  __shared__ float sm[8];
  int wid = tid >> 6;
  if ((tid & 63) == 0) { sm[wid] = s; sm[4 + wid] = q; }
  __syncthreads();
  s = sm[0] + sm[1] + sm[2] + sm[3];
  q = sm[4] + sm[5] + sm[6] + sm[7];
  float mean = s * (1.f / DD);
  float var = q * (1.f / DD) - mean * mean;
  float rs = rsqrtf(var + 1e-5f);
  const float4 wv = *(const float4*)(w + tid * 4);
  const float4 bv = *(const float4*)(b + tid * 4);
  u16 o[4];
  o[0] = f2bf((v.x - mean) * rs * wv.x + bv.x);
  o[1] = f2bf((v.y - mean) * rs * wv.y + bv.y);
  o[2] = f2bf((v.z - mean) * rs * wv.z + bv.z);
  o[3] = f2bf((v.w - mean) * rs * wv.w + bv.w);
  *(uint64_t*)(out + (size_t)m * DD + tid * 4) = *(uint64_t*)o;
}

// final LN on the two last-token rows, fp32 out
__global__ __launch_bounds__(256) void k_lnf(const float* __restrict__ x,
                                             const float* __restrict__ w,
                                             const float* __restrict__ b,
                                             float* __restrict__ out) {
  int bb = blockIdx.x, tid = threadIdx.x;
  int m = bb * TTT + (TTT - 1);
  const float4 v = *(const float4*)(x + (size_t)m * DD + tid * 4);
  float s = v.x + v.y + v.z + v.w;
  float q = v.x * v.x + v.y * v.y + v.z * v.z + v.w * v.w;
#pragma unroll
  for (int off = 1; off < 64; off <<= 1) { s += __shfl_xor(s, off); q += __shfl_xor(q, off); }
  __shared__ float sm[8];
  int wid = tid >> 6;
  if ((tid & 63) == 0) { sm[wid] = s; sm[4 + wid] = q; }
  __syncthreads();
  s = sm[0] + sm[1] + sm[2] + sm[3];
  q = sm[4] + sm[5] + sm[6] + sm[7];
  float mean = s * (1.f / DD);
  float var = q * (1.f / DD) - mean * mean;
  float rs = rsqrtf(var + 1e-5f);
  const float4 wv = *(const float4*)(w + tid * 4);
  const float4 bv = *(const float4*)(b + tid * 4);
  float4 o;
  o.x = (v.x - mean) * rs * wv.x + bv.x;
  o.y = (v.y - mean) * rs * wv.y + bv.y;
  o.z = (v.z - mean) * rs * wv.z + bv.z;
  o.w = (v.w - mean) * rs * wv.w + bv.w;
  *(float4*)(out + (size_t)bb * DD + tid * 4) = o;
}

// ---------------- weight transpose fp32[K,N] -> bf16[N,K] ----------------
__global__ __launch_bounds__(256) void k_wtrans(const float* __restrict__ W,
                                                u16* __restrict__ Wt, int K, int N) {
  __shared__ float tile[32][33];
  int k0 = blockIdx.x * 32, n0 = blockIdx.y * 32;
  int tx = threadIdx.x & 31, ty = threadIdx.x >> 5;  // ty in [0,8)
#pragma unroll
  for (int i = 0; i < 4; ++i)
    tile[ty + i * 8][tx] = W[(size_t)(k0 + ty + i * 8) * N + n0 + tx];
  __syncthreads();
#pragma unroll
  for (int i = 0; i < 4; ++i)
    Wt[(size_t)(n0 + ty + i * 8) * K + k0 + tx] = f2bf(tile[tx][ty + i * 8]);
}

// ---------------- GEMM: out = A[M,K] * Bt[N,K]^T + bias ----------------
// EPI 0: bf16 out; EPI 1: xres += (single-owner); EPI 2: gelu->bf16;
// EPI 3: atomicAdd into xres (split-K), bias added by bz==0 chunk only.
template <int EPI>
__global__ __launch_bounds__(256) void k_gemm(const u16* __restrict__ A,
                                              const u16* __restrict__ Bt,
                                              const float* __restrict__ bias,
                                              u16* __restrict__ outb,
                                              float* __restrict__ xres,
                                              int M, int N, int K, int KC) {
  __shared__ u16 As[128 * 64];
  __shared__ u16 Bs[128 * 64];
  // bijective XCD swizzle (m204): each XCD gets a contiguous logical chunk
  const int nbx = gridDim.x, nby = gridDim.y;
  const int nwg = nbx * nby * gridDim.z;
  const int orig = blockIdx.x + nbx * (blockIdx.y + nby * blockIdx.z);
  const int qq = nwg >> 3, rr = nwg & 7;
  const int xcd = orig & 7, pos = orig >> 3;
  const int wg = (xcd < rr ? xcd * (qq + 1) : rr * (qq + 1) + (xcd - rr) * qq) + pos;
  const int bx = wg % nbx;
  const int tmpw = wg / nbx;
  const int by = tmpw % nby, bz = tmpw / nby;

  const int tid = threadIdx.x;
  const int lane = tid & 63, wid = tid >> 6;
  const int wr = wid >> 1, wc = wid & 1;
  const int l15 = lane & 15, l4 = lane >> 4;
  const int m0 = bx * 128, n0 = by * 128;
  f32x4 acc[4][4] = {};

  const int srow = tid >> 3, scol = (tid & 7) * 8;
  const int k0beg = bz * KC, k0end = k0beg + KC;
  for (int k0 = k0beg; k0 < k0end; k0 += 64) {
#pragma unroll
    for (int it = 0; it < 4; ++it) {
      GLDS16(A + (size_t)(m0 + srow + it * 32) * K + k0 + scol, (char*)As + it * 4096 + tid * 16);
      GLDS16(Bt + (size_t)(n0 + srow + it * 32) * K + k0 + scol, (char*)Bs + it * 4096 + tid * 16);
    }
    __syncthreads();
#pragma unroll
    for (int ks = 0; ks < 2; ++ks) {
      bf16x8 af[4], bfr[4];
#pragma unroll
      for (int i = 0; i < 4; ++i)
        af[i] = *(const bf16x8*)(As + (wr * 64 + i * 16 + l15) * 64 + ks * 32 + l4 * 8);
#pragma unroll
      for (int j = 0; j < 4; ++j)
        bfr[j] = *(const bf16x8*)(Bs + (wc * 64 + j * 16 + l15) * 64 + ks * 32 + l4 * 8);
#pragma unroll
      for (int i = 0; i < 4; ++i)
#pragma unroll
        for (int j = 0; j < 4; ++j)
          acc[i][j] = __builtin_amdgcn_mfma_f32_16x16x32_bf16(af[i], bfr[j], acc[i][j], 0, 0, 0);
    }
    __syncthreads();
  }
#pragma unroll
  for (int j = 0; j < 4; ++j) {
    const int col = n0 + wc * 64 + j * 16 + l15;
    const float bs = (EPI == 3 && bz != 0) ? 0.f : bias[col];
#pragma unroll
    for (int i = 0; i < 4; ++i) {
#pragma unroll
      for (int r = 0; r < 4; ++r) {
        const int row = m0 + wr * 64 + i * 16 + l4 * 4 + r;
        float v = acc[i][j][r] + bs;
        if (EPI == 0) {
          outb[(size_t)row * N + col] = f2bf(v);
        } else if (EPI == 1) {
          xres[(size_t)row * N + col] += v;
        } else if (EPI == 2) {
          float g = 0.5f * v * (1.f + erff(v * 0.70710678118f));
          outb[(size_t)row * N + col] = f2bf(g);
        } else {
          atomicAdd(&xres[(size_t)row * N + col], v);
        }
      }
    }
  }
}

// ---------------- K/V repack via LDS de-interleave ----------------
// qkv col d = h*16 + n (head n, dim h). K -> Kb[bn][t][h]; V -> Vt[bn][h][t].
__global__ __launch_bounds__(256) void k_repack(const u16* __restrict__ qkv,
                                                u16* __restrict__ Kb,
                                                u16* __restrict__ Vt) {
  __shared__ u16 tile[16 * 1024];
  const int tid = threadIdx.x;
  const int m0 = blockIdx.x * 16;
  const int part = blockIdx.y + 1;     // 1=K, 2=V
  const int b = m0 >> 10;
  const int tg0 = m0 & (TTT - 1);
  // stage with head swizzle: e' = e ^ ((h&7)<<3); keeps 16B chunks contiguous
#pragma unroll
  for (int p = 0; p < 8; ++p) {
    int row = p * 2 + (tid >> 7);
    int col8 = (tid & 127) * 8;
    bf16x8 v = *(const bf16x8*)(qkv + (size_t)(m0 + row) * 3072 + part * 1024 + col8);
    int e = col8 ^ (((col8 >> 4) & 7) << 3);
    *(bf16x8*)(tile + row * 1024 + e) = v;
  }
  __syncthreads();
  const int lane = tid & 63, wid = tid >> 6;
  if (part == 1) {
    // K: jobs (n,t) = 256; wave writes 128B contiguous (lane = h)
    for (int p = wid; p < 256; p += 4) {
      int t = p >> 4, n = p & 15;
      int e = (lane * 16 + n) ^ ((lane & 7) << 3);
      u16 val = tile[t * 1024 + e];
      Kb[(((size_t)(b * 16 + n)) * TTT + tg0 + t) * 64 + lane] = val;
    }
  } else {
    // V transposed: lane = h gathers 8 t, writes 16B chunk
    for (int p = wid; p < 32; p += 4) {
      int n = p >> 1, tc = p & 1;
      int e = (lane * 16 + n) ^ ((lane & 7) << 3);
      u16 val8[8];
#pragma unroll
      for (int k = 0; k < 8; ++k) val8[k] = tile[(tc * 8 + k) * 1024 + e];
      *(bf16x8*)(Vt + (((size_t)(b * 16 + n)) * 64 + lane) * TTT + tg0 + tc * 8) =
          *(bf16x8*)val8;
    }
  }
}

// ---------------- flash attention (causal), 64 q-rows, 128-key tiles ----------------
__global__ __launch_bounds__(256) void k_attn(const u16* __restrict__ qkv,
                                              const u16* __restrict__ Kb,
                                              const u16* __restrict__ Vt,
                                              u16* __restrict__ attout) {
  __shared__ u16 Ks[128 * 64];
  __shared__ u16 Vs[64 * 128];
  __shared__ u16 Ps[4][16 * 136];

  const int tid = threadIdx.x;
  const int lane = tid & 63, wid = tid >> 6;
  const int l15 = lane & 15, l4 = lane >> 4;
  const int bn = blockIdx.x;                 // b*16 + n
  const int qtr = 15 - (int)blockIdx.y;      // heavy tiles first
  const int q0 = qtr * 64;
  const int b = bn >> 4, nh = bn & 15;

  // Q frags straight from qkv (strided, one-time, L2-hot)
  const int qrow = q0 + wid * 16 + l15;
  const u16* qsrc = qkv + (size_t)(b * TTT + qrow) * 3072 + nh;
  bf16x8 aq[2];
#pragma unroll
  for (int ks = 0; ks < 2; ++ks) {
    short tmp[8];
#pragma unroll
    for (int j = 0; j < 8; ++j) tmp[j] = (short)qsrc[(ks * 32 + l4 * 8 + j) * 16];
    aq[ks] = *(bf16x8*)tmp;
  }

  const char* Kg0 = (const char*)(Kb + (size_t)bn * TTT * 64);
  const char* Vg0 = (const char*)(Vt + (size_t)bn * 64 * TTT);

  float m_run[4], l_part[4];
  f32x4 o[4] = {};
#pragma unroll
  for (int r = 0; r < 4; ++r) { m_run[r] = -1e30f; l_part[r] = 0.f; }

  const int ntk = (qtr >> 1) + 1;
  for (int kt = 0; kt < ntk; ++kt) {
    // stage K [128 keys][64 h] rows of 128B, XOR swizzle both sides
#pragma unroll
    for (int it = 0; it < 4; ++it) {
      int L = it * 4096 + tid * 16;
      int Ls = L ^ (((L >> 7) & 7) << 4);
      GLDS16(Kg0 + (size_t)kt * 16384 + Ls, (char*)Ks + L);
    }
    // stage V [64 h][128 keys] rows of 256B
#pragma unroll
    for (int it = 0; it < 4; ++it) {
      int L = it * 4096 + tid * 16;
      int Ls = L ^ (((L >> 8) & 7) << 4);
      int hrow = Ls >> 8, cb = Ls & 255;
      GLDS16(Vg0 + (size_t)hrow * 2048 + kt * 256 + cb, (char*)Vs + L);
    }
    __syncthreads();

    // S = Q K^T  (8 column-frags of 16 keys)
    f32x4 sf[8];
#pragma unroll
    for (int cf = 0; cf < 8; ++cf) {
      f32x4 z = {};
#pragma unroll
      for (int ks = 0; ks < 2; ++ks) {
        int P = (cf * 16 + l15) * 128 + (ks * 32 + l4 * 8) * 2;
        bf16x8 kb = *(const bf16x8*)((const char*)Ks + (P ^ (((P >> 7) & 7) << 4)));
        z = __builtin_amdgcn_mfma_f32_16x16x32_bf16(aq[ks], kb, z, 0, 0, 0);
      }
      sf[cf] = z;
    }
    const bool lastkt = (kt == ntk - 1);
#pragma unroll
    for (int cf = 0; cf < 8; ++cf)
#pragma unroll
      for (int r = 0; r < 4; ++r) {
        float s = sf[cf][r] * 0.125f;
        if (lastkt) {
          int kg = kt * 128 + cf * 16 + l15;
          int qg = q0 + wid * 16 + l4 * 4 + r;
          if (kg > qg) s = -1e30f;
        }
        sf[cf][r] = s;
      }
    // online softmax: cross-lane reduce ONLY for max; l-sum deferred per-lane
    float fac[4];
#pragma unroll
    for (int r = 0; r < 4; ++r) {
      float tm = sf[0][r];
#pragma unroll
      for (int cf = 1; cf < 8; ++cf) tm = fmaxf(tm, sf[cf][r]);
#pragma unroll
      for (int off = 1; off < 16; off <<= 1) tm = fmaxf(tm, __shfl_xor(tm, off));
      float mnew = fmaxf(m_run[r], tm);
      fac[r] = __expf(m_run[r] - mnew);
      m_run[r] = mnew;
      float ps = 0.f;
#pragma unroll
      for (int cf = 0; cf < 8; ++cf) {
        float p = __expf(sf[cf][r] - mnew);
        sf[cf][r] = p;
        ps += p;
      }
      l_part[r] = l_part[r] * fac[r] + ps;
    }
    // P -> LDS (bf16) per-wave
#pragma unroll
    for (int cf = 0; cf < 8; ++cf)
#pragma unroll
      for (int r = 0; r < 4; ++r)
        Ps[wid][(l4 * 4 + r) * 136 + cf * 16 + l15] = f2bf(sf[cf][r]);
    // rescale O
#pragma unroll
    for (int hf = 0; hf < 4; ++hf)
#pragma unroll
      for (int r = 0; r < 4; ++r) o[hf][r] *= fac[r];
    // PV
    bf16x8 pa[4];
#pragma unroll
    for (int ks = 0; ks < 4; ++ks)
      pa[ks] = *(const bf16x8*)&Ps[wid][l15 * 136 + ks * 32 + l4 * 8];
#pragma unroll
    for (int hf = 0; hf < 4; ++hf) {
#pragma unroll
      for (int ks = 0; ks < 4; ++ks) {
        int P = (hf * 16 + l15) * 256 + (ks * 32 + l4 * 8) * 2;
        bf16x8 vb = *(const bf16x8*)((const char*)Vs + (P ^ (((P >> 8) & 7) << 4)));
        o[hf] = __builtin_amdgcn_mfma_f32_16x16x32_bf16(pa[ks], vb, o[hf], 0, 0, 0);
      }
    }
    __syncthreads();
  }
  // final l reduction (once) and write
  float lsum[4];
#pragma unroll
  for (int r = 0; r < 4; ++r) {
    float s = l_part[r];
#pragma unroll
    for (int off = 1; off < 16; off <<= 1) s += __shfl_xor(s, off);
    lsum[r] = s;
  }
#pragma unroll
  for (int hf = 0; hf < 4; ++hf)
#pragma unroll
    for (int r = 0; r < 4; ++r) {
      float val = o[hf][r] / lsum[r];
      size_t row = (size_t)b * TTT + q0 + wid * 16 + l4 * 4 + r;
      attout[row * DD + nh * 64 + hf * 16 + l15] = f2bf(val);
    }
}

// ---------------- lm head: out[b][v] = dot(xlnf[b], wte[v]) fp32 ----------------
__global__ __launch_bounds__(256) void k_head(const float* __restrict__ xlnf,
                                              const float* __restrict__ wte,
                                              float* __restrict__ out) {
  __shared__ float xs[2 * DD];
  int tid = threadIdx.x;
#pragma unroll
  for (int i = 0; i < 2; ++i)
    *(float4*)(xs + i * DD + tid * 4) = *(const float4*)(xlnf + i * DD + tid * 4);
  __syncthreads();
  int wid = tid >> 6, lane = tid & 63;
  for (int v = blockIdx.x * 4 + wid; v < VVV; v += gridDim.x * 4) {
    const float* wr = wte + (size_t)v * DD;
    float a0 = 0.f, a1 = 0.f;
#pragma unroll
    for (int j = 0; j < 4; ++j) {
      const float4 wv = *(const float4*)(wr + lane * 16 + j * 4);
      const float4 x0 = *(const float4*)(xs + lane * 16 + j * 4);
      const float4 x1 = *(const float4*)(xs + DD + lane * 16 + j * 4);
      a0 += wv.x * x0.x + wv.y * x0.y + wv.z * x0.z + wv.w * x0.w;
      a1 += wv.x * x1.x + wv.y * x1.y + wv.z * x1.z + wv.w * x1.w;
    }
#pragma unroll
    for (int off = 1; off < 64; off <<= 1) { a0 += __shfl_xor(a0, off); a1 += __shfl_xor(a1, off); }
    if (lane == 0) { out[v] = a0; out[VVV + v] = a1; }
  }
}

extern "C" void kernel_launch(void* const* d_in, const int* in_sizes, int n_in,
                              void* d_out, int out_size, void* d_ws, size_t ws_size,
                              hipStream_t stream) {
  const int* tokens    = (const int*)d_in[0];
  const float* wte     = (const float*)d_in[1];
  const float* wpe     = (const float*)d_in[2];
  const float* ln1_w   = (const float*)d_in[3];
  const float* ln1_b   = (const float*)d_in[4];
  const float* attn_w  = (const float*)d_in[5];
  const float* attn_b  = (const float*)d_in[6];
  const float* aproj_w = (const float*)d_in[7];
  const float* aproj_b = (const float*)d_in[8];
  const float* ln2_w   = (const float*)d_in[9];
  const float* ln2_b   = (const float*)d_in[10];
  const float* fc_w    = (const float*)d_in[11];
  const float* fc_b    = (const float*)d_in[12];
  const float* proj_w  = (const float*)d_in[13];
  const float* proj_b  = (const float*)d_in[14];
  const float* lnf_w   = (const float*)d_in[15];
  const float* lnf_b   = (const float*)d_in[16];

  char* ws = (char*)d_ws;
  float* x    = (float*)(ws);                    // 8 MB
  u16* h      = (u16*)(ws + (8u << 20));         // 4 MB
  u16* qkv    = (u16*)(ws + (12u << 20));        // 12 MB
  u16* Kb     = (u16*)(ws + (24u << 20));        // 4 MB
  u16* Vt     = (u16*)(ws + (28u << 20));        // 4 MB
  u16* attb   = (u16*)(ws + (32u << 20));        // 4 MB
  u16* mlph   = (u16*)(ws + (36u << 20));        // 16 MB
  u16* wt     = (u16*)(ws + (52u << 20));        // 8 MB
  float* xlnf = (float*)(ws + (60u << 20));      // 8 KB
  float* out  = (float*)d_out;

  k_embed<<<MR, 256, 0, stream>>>(tokens, wte, wpe, x);

  for (int l = 0; l < 12; ++l) {
    k_ln<<<MR, 256, 0, stream>>>(x, ln1_w + l * DD, ln1_b + l * DD, h);
    k_wtrans<<<dim3(32, 96), 256, 0, stream>>>(attn_w + (size_t)l * DD * 3 * DD, wt, 1024, 3072);
    k_gemm<0><<<dim3(16, 24, 1), 256, 0, stream>>>(h, wt, attn_b + (size_t)l * 3 * DD, qkv, nullptr, MR, 3072, 1024, 1024);
    k_repack<<<dim3(128, 2), 256, 0, stream>>>(qkv, Kb, Vt);
    k_attn<<<dim3(32, 16), 256, 0, stream>>>(qkv, Kb, Vt, attb);
    k_wtrans<<<dim3(32, 32), 256, 0, stream>>>(aproj_w + (size_t)l * DD * DD, wt, 1024, 1024);
    k_gemm<1><<<dim3(16, 8, 1), 256, 0, stream>>>(attb, wt, aproj_b + (size_t)l * DD, nullptr, x, MR, 1024, 1024, 1024);
    k_ln<<<MR, 256, 0, stream>>>(x, ln2_w + l * DD, ln2_b + l * DD, h);
    k_wtrans<<<dim3(32, 128), 256, 0, stream>>>(fc_w + (size_t)l * DD * FFF, wt, 1024, 4096);
    k_gemm<2><<<dim3(16, 32, 1), 256, 0, stream>>>(h, wt, fc_b + (size_t)l * FFF, mlph, nullptr, MR, 4096, 1024, 1024);
    k_wtrans<<<dim3(128, 32), 256, 0, stream>>>(proj_w + (size_t)l * FFF * DD, wt, 4096, 1024);
    k_gemm<3><<<dim3(16, 8, 4), 256, 0, stream>>>(mlph, wt, proj_b + (size_t)l * DD, nullptr, x, MR, 1024, 4096, 1024);
  }
  k_lnf<<<2, 256, 0, stream>>>(x, lnf_w, lnf_b, xlnf);
  k_head<<<512, 256, 0, stream>>>(xlnf, wte, out);
}

// Round 3
// 2397.156 us; speedup vs baseline: 1.4086x; 1.0692x over previous
//
#include <hip/hip_runtime.h>
#include <cstdint>
#include <math.h>

// GPT-2 forward, MI355X. B=2, T=1024, D=1024, NH=16, HD=64, L=12, F=4096, V=50257.
// fp32 residual; bf16 MFMA GEMMs (128^2 tile, double-buffered 2-phase prefetch,
// XCD swizzle, split-K for aproj/proj); flash attention 128-key tiles; fast-erf GELU.

using u16 = unsigned short;
using bf16x8 = __attribute__((ext_vector_type(8))) short;
using f32x4 = __attribute__((ext_vector_type(4))) float;

#define GLDS16(g, l)                                                        \
  __builtin_amdgcn_global_load_lds(                                         \
      (const __attribute__((address_space(1))) void*)(g),                   \
      (__attribute__((address_space(3))) void*)(l), 16, 0, 0)

__device__ __forceinline__ u16 f2bf(float f) {
  union { float f; unsigned u; } t; t.f = f;
  unsigned r = t.u + 0x7fffu + ((t.u >> 16) & 1u);
  return (u16)(r >> 16);
}

// A&S 7.1.26, |err| <= 1.5e-7
__device__ __forceinline__ float fast_erf(float x) {
  float ax = fabsf(x);
  float t = 1.f / (1.f + 0.3275911f * ax);
  float y = t * (0.254829592f +
            t * (-0.284496736f +
            t * (1.421413741f +
            t * (-1.453152027f +
            t * 1.061405429f))));
  float r = 1.f - y * __expf(-ax * ax);
  return copysignf(r, x);
}

#define DD 1024
#define TTT 1024
#define MR 2048     // B*T
#define FFF 4096
#define VVV 50257

// ---------------- embedding ----------------
__global__ __launch_bounds__(256) void k_embed(const int* __restrict__ tokens,
                                               const float* __restrict__ wte,
                                               const float* __restrict__ wpe,
                                               float* __restrict__ x) {
  int m = blockIdx.x, d = threadIdx.x * 4;
  int t = m & (TTT - 1);
  int tok = tokens[m];
  const float4 a = *(const float4*)(wte + (size_t)tok * DD + d);
  const float4 p = *(const float4*)(wpe + (size_t)t * DD + d);
  float4 o; o.x = a.x + p.x; o.y = a.y + p.y; o.z = a.z + p.z; o.w = a.w + p.w;
  *(float4*)(x + (size_t)m * DD + d) = o;
}

// ---------------- layernorm -> bf16 ----------------
__global__ __launch_bounds__(256) void k_ln(const float* __restrict__ x,
                                            const float* __restrict__ w,
                                            const float* __restrict__ b,
                                            u16* __restrict__ out) {
  int m = blockIdx.x, tid = threadIdx.x;
  const float4 v = *(const float4*)(x + (size_t)m * DD + tid * 4);
  float s = v.x + v.y + v.z + v.w;
  float q = v.x * v.x + v.y * v.y + v.z * v.z + v.w * v.w;
#pragma unroll
  for (int off = 1; off < 64; off <<= 1) { s += __shfl_xor(s, off); q += __shfl_xor(q, off); }
  __shared__ float sm[8];
  int wid = tid >> 6;
  if ((tid & 63) == 0) { sm[wid] = s; sm[4 + wid] = q; }
  __syncthreads();
  s = sm[0] + sm[1] + sm[2] + sm[3];
  q = sm[4] + sm[5] + sm[6] + sm[7];
  float mean = s * (1.f / DD);
  float var = q * (1.f / DD) - mean * mean;
  float rs = rsqrtf(var + 1e-5f);
  const float4 wv = *(const float4*)(w + tid * 4);
  const float4 bv = *(const float4*)(b + tid * 4);
  u16 o[4];
  o[0] = f2bf((v.x - mean) * rs * wv.x + bv.x);
  o[1] = f2bf((v.y - mean) * rs * wv.y + bv.y);
  o[2] = f2bf((v.z - mean) * rs * wv.z + bv.z);
  o[3] = f2bf((v.w - mean) * rs * wv.w + bv.w);
  *(uint64_t*)(out + (size_t)m * DD + tid * 4) = *(uint64_t*)o;
}

// final LN on the two last-token rows, fp32 out
__global__ __launch_bounds__(256) void k_lnf(const float* __restrict__ x,
                                             const float* __restrict__ w,
                                             const float* __restrict__ b,
                                             float* __restrict__ out) {
  int bb = blockIdx.x, tid = threadIdx.x;
  int m = bb * TTT + (TTT - 1);
  const float4 v = *(const float4*)(x + (size_t)m * DD + tid * 4);
  float s = v.x + v.y + v.z + v.w;
  float q = v.x * v.x + v.y * v.y + v.z * v.z + v.w * v.w;
#pragma unroll
  for (int off = 1; off < 64; off <<= 1) { s += __shfl_xor(s, off); q += __shfl_xor(q, off); }
  __shared__ float sm[8];
  int wid = tid >> 6;
  if ((tid & 63) == 0) { sm[wid] = s; sm[4 + wid] = q; }
  __syncthreads();
  s = sm[0] + sm[1] + sm[2] + sm[3];
  q = sm[4] + sm[5] + sm[6] + sm[7];
  float mean = s * (1.f / DD);
  float var = q * (1.f / DD) - mean * mean;
  float rs = rsqrtf(var + 1e-5f);
  const float4 wv = *(const float4*)(w + tid * 4);
  const float4 bv = *(const float4*)(b + tid * 4);
  float4 o;
  o.x = (v.x - mean) * rs * wv.x + bv.x;
  o.y = (v.y - mean) * rs * wv.y + bv.y;
  o.z = (v.z - mean) * rs * wv.z + bv.z;
  o.w = (v.w - mean) * rs * wv.w + bv.w;
  *(float4*)(out + (size_t)bb * DD + tid * 4) = o;
}

// ---------------- weight transpose fp32[K,N] -> bf16[N,K] ----------------
__global__ __launch_bounds__(256) void k_wtrans(const float* __restrict__ W,
                                                u16* __restrict__ Wt, int K, int N) {
  __shared__ float tile[32][33];
  int k0 = blockIdx.x * 32, n0 = blockIdx.y * 32;
  int tx = threadIdx.x & 31, ty = threadIdx.x >> 5;  // ty in [0,8)
#pragma unroll
  for (int i = 0; i < 4; ++i)
    tile[ty + i * 8][tx] = W[(size_t)(k0 + ty + i * 8) * N + n0 + tx];
  __syncthreads();
#pragma unroll
  for (int i = 0; i < 4; ++i)
    Wt[(size_t)(n0 + ty + i * 8) * K + k0 + tx] = f2bf(tile[tx][ty + i * 8]);
}

// ---------------- GEMM: out = A[M,K] * Bt[N,K]^T + bias ----------------
// 2-phase double-buffered: STAGE(t+1) issued BEFORE compute(t); one barrier/k-step.
// EPI 0: bf16 out; EPI 1: xres += (single-owner); EPI 2: gelu->bf16;
// EPI 3: atomicAdd into xres (split-K), bias added by bz==0 chunk only.
template <int EPI>
__global__ __launch_bounds__(256) void k_gemm(const u16* __restrict__ A,
                                              const u16* __restrict__ Bt,
                                              const float* __restrict__ bias,
                                              u16* __restrict__ outb,
                                              float* __restrict__ xres,
                                              int M, int N, int K, int KC) {
  __shared__ u16 As[2][128 * 64];
  __shared__ u16 Bs[2][128 * 64];
  // bijective XCD swizzle (m204)
  const int nbx = gridDim.x, nby = gridDim.y;
  const int nwg = nbx * nby * gridDim.z;
  const int orig = blockIdx.x + nbx * (blockIdx.y + nby * blockIdx.z);
  const int qq = nwg >> 3, rr = nwg & 7;
  const int xcd = orig & 7, pos = orig >> 3;
  const int wg = (xcd < rr ? xcd * (qq + 1) : rr * (qq + 1) + (xcd - rr) * qq) + pos;
  const int bx = wg % nbx;
  const int tmpw = wg / nbx;
  const int by = tmpw % nby, bz = tmpw / nby;

  const int tid = threadIdx.x;
  const int lane = tid & 63, wid = tid >> 6;
  const int wr = wid >> 1, wc = wid & 1;
  const int l15 = lane & 15, l4 = lane >> 4;
  const int m0 = bx * 128, n0 = by * 128;
  f32x4 acc[4][4] = {};

  const int srow = tid >> 3, scol = (tid & 7) * 8;
  const int k0beg = bz * KC;
  const int nt = KC >> 6;

  const u16* Ap = A + (size_t)(m0 + srow) * K + scol;
  const u16* Bp = Bt + (size_t)(n0 + srow) * K + scol;

#define STAGE(buf, k0)                                                      \
  {                                                                         \
    _Pragma("unroll")                                                       \
    for (int it = 0; it < 4; ++it) {                                        \
      GLDS16(Ap + (size_t)it * 32 * K + (k0), (char*)As[buf] + it * 4096 + tid * 16); \
      GLDS16(Bp + (size_t)it * 32 * K + (k0), (char*)Bs[buf] + it * 4096 + tid * 16); \
    }                                                                       \
  }

  STAGE(0, k0beg);
  __syncthreads();
  for (int t = 0; t < nt; ++t) {
    if (t + 1 < nt) STAGE((t + 1) & 1, k0beg + (t + 1) * 64);
    const u16* Ab = As[t & 1];
    const u16* Bb = Bs[t & 1];
#pragma unroll
    for (int ks = 0; ks < 2; ++ks) {
      bf16x8 af[4], bfr[4];
#pragma unroll
      for (int i = 0; i < 4; ++i)
        af[i] = *(const bf16x8*)(Ab + (wr * 64 + i * 16 + l15) * 64 + ks * 32 + l4 * 8);
#pragma unroll
      for (int j = 0; j < 4; ++j)
        bfr[j] = *(const bf16x8*)(Bb + (wc * 64 + j * 16 + l15) * 64 + ks * 32 + l4 * 8);
#pragma unroll
      for (int i = 0; i < 4; ++i)
#pragma unroll
        for (int j = 0; j < 4; ++j)
          acc[i][j] = __builtin_amdgcn_mfma_f32_16x16x32_bf16(af[i], bfr[j], acc[i][j], 0, 0, 0);
    }
    __syncthreads();
  }
#undef STAGE
#pragma unroll
  for (int j = 0; j < 4; ++j) {
    const int col = n0 + wc * 64 + j * 16 + l15;
    const float bs = (EPI == 3 && bz != 0) ? 0.f : bias[col];
#pragma unroll
    for (int i = 0; i < 4; ++i) {
#pragma unroll
      for (int r = 0; r < 4; ++r) {
        const int row = m0 + wr * 64 + i * 16 + l4 * 4 + r;
        float v = acc[i][j][r] + bs;
        if (EPI == 0) {
          outb[(size_t)row * N + col] = f2bf(v);
        } else if (EPI == 1) {
          xres[(size_t)row * N + col] += v;
        } else if (EPI == 2) {
          float g = 0.5f * v * (1.f + fast_erf(v * 0.70710678118f));
          outb[(size_t)row * N + col] = f2bf(g);
        } else {
          atomicAdd(&xres[(size_t)row * N + col], v);
        }
      }
    }
  }
}

// ---------------- K/V repack via LDS de-interleave ----------------
// qkv col d = h*16 + n (head n, dim h). K -> Kb[bn][t][h]; V -> Vt[bn][h][t].
__global__ __launch_bounds__(256) void k_repack(const u16* __restrict__ qkv,
                                                u16* __restrict__ Kb,
                                                u16* __restrict__ Vt) {
  __shared__ u16 tile[16 * 1024];
  const int tid = threadIdx.x;
  const int m0 = blockIdx.x * 16;
  const int part = blockIdx.y + 1;     // 1=K, 2=V
  const int b = m0 >> 10;
  const int tg0 = m0 & (TTT - 1);
#pragma unroll
  for (int p = 0; p < 8; ++p) {
    int row = p * 2 + (tid >> 7);
    int col8 = (tid & 127) * 8;
    bf16x8 v = *(const bf16x8*)(qkv + (size_t)(m0 + row) * 3072 + part * 1024 + col8);
    int e = col8 ^ (((col8 >> 4) & 7) << 3);
    *(bf16x8*)(tile + row * 1024 + e) = v;
  }
  __syncthreads();
  const int lane = tid & 63, wid = tid >> 6;
  if (part == 1) {
    for (int p = wid; p < 256; p += 4) {
      int t = p >> 4, n = p & 15;
      int e = (lane * 16 + n) ^ ((lane & 7) << 3);
      u16 val = tile[t * 1024 + e];
      Kb[(((size_t)(b * 16 + n)) * TTT + tg0 + t) * 64 + lane] = val;
    }
  } else {
    for (int p = wid; p < 32; p += 4) {
      int n = p >> 1, tc = p & 1;
      int e = (lane * 16 + n) ^ ((lane & 7) << 3);
      u16 val8[8];
#pragma unroll
      for (int k = 0; k < 8; ++k) val8[k] = tile[(tc * 8 + k) * 1024 + e];
      *(bf16x8*)(Vt + (((size_t)(b * 16 + n)) * 64 + lane) * TTT + tg0 + tc * 8) =
          *(bf16x8*)val8;
    }
  }
}

// ---------------- flash attention (causal), 64 q-rows, 128-key tiles ----------------
__global__ __launch_bounds__(256) void k_attn(const u16* __restrict__ qkv,
                                              const u16* __restrict__ Kb,
                                              const u16* __restrict__ Vt,
                                              u16* __restrict__ attout) {
  __shared__ u16 Ks[128 * 64];
  __shared__ u16 Vs[64 * 128];
  __shared__ u16 Ps[4][16 * 136];

  const int tid = threadIdx.x;
  const int lane = tid & 63, wid = tid >> 6;
  const int l15 = lane & 15, l4 = lane >> 4;
  const int bn = blockIdx.x;                 // b*16 + n
  const int qtr = 15 - (int)blockIdx.y;      // heavy tiles first
  const int q0 = qtr * 64;
  const int b = bn >> 4, nh = bn & 15;

  const int qrow = q0 + wid * 16 + l15;
  const u16* qsrc = qkv + (size_t)(b * TTT + qrow) * 3072 + nh;
  bf16x8 aq[2];
#pragma unroll
  for (int ks = 0; ks < 2; ++ks) {
    short tmp[8];
#pragma unroll
    for (int j = 0; j < 8; ++j) tmp[j] = (short)qsrc[(ks * 32 + l4 * 8 + j) * 16];
    aq[ks] = *(bf16x8*)tmp;
  }

  const char* Kg0 = (const char*)(Kb + (size_t)bn * TTT * 64);
  const char* Vg0 = (const char*)(Vt + (size_t)bn * 64 * TTT);

  float m_run[4], l_part[4];
  f32x4 o[4] = {};
#pragma unroll
  for (int r = 0; r < 4; ++r) { m_run[r] = -1e30f; l_part[r] = 0.f; }

  const int ntk = (qtr >> 1) + 1;
  for (int kt = 0; kt < ntk; ++kt) {
#pragma unroll
    for (int it = 0; it < 4; ++it) {
      int L = it * 4096 + tid * 16;
      int Ls = L ^ (((L >> 7) & 7) << 4);
      GLDS16(Kg0 + (size_t)kt * 16384 + Ls, (char*)Ks + L);
    }
#pragma unroll
    for (int it = 0; it < 4; ++it) {
      int L = it * 4096 + tid * 16;
      int Ls = L ^ (((L >> 8) & 7) << 4);
      int hrow = Ls >> 8, cb = Ls & 255;
      GLDS16(Vg0 + (size_t)hrow * 2048 + kt * 256 + cb, (char*)Vs + L);
    }
    __syncthreads();

    f32x4 sf[8];
#pragma unroll
    for (int cf = 0; cf < 8; ++cf) {
      f32x4 z = {};
#pragma unroll
      for (int ks = 0; ks < 2; ++ks) {
        int P = (cf * 16 + l15) * 128 + (ks * 32 + l4 * 8) * 2;
        bf16x8 kb = *(const bf16x8*)((const char*)Ks + (P ^ (((P >> 7) & 7) << 4)));
        z = __builtin_amdgcn_mfma_f32_16x16x32_bf16(aq[ks], kb, z, 0, 0, 0);
      }
      sf[cf] = z;
    }
    const bool lastkt = (kt == ntk - 1);
#pragma unroll
    for (int cf = 0; cf < 8; ++cf)
#pragma unroll
      for (int r = 0; r < 4; ++r) {
        float s = sf[cf][r] * 0.125f;
        if (lastkt) {
          int kg = kt * 128 + cf * 16 + l15;
          int qg = q0 + wid * 16 + l4 * 4 + r;
          if (kg > qg) s = -1e30f;
        }
        sf[cf][r] = s;
      }
    float fac[4];
#pragma unroll
    for (int r = 0; r < 4; ++r) {
      float tm = sf[0][r];
#pragma unroll
      for (int cf = 1; cf < 8; ++cf) tm = fmaxf(tm, sf[cf][r]);
#pragma unroll
      for (int off = 1; off < 16; off <<= 1) tm = fmaxf(tm, __shfl_xor(tm, off));
      float mnew = fmaxf(m_run[r], tm);
      fac[r] = __expf(m_run[r] - mnew);
      m_run[r] = mnew;
      float ps = 0.f;
#pragma unroll
      for (int cf = 0; cf < 8; ++cf) {
        float p = __expf(sf[cf][r] - mnew);
        sf[cf][r] = p;
        ps += p;
      }
      l_part[r] = l_part[r] * fac[r] + ps;
    }
#pragma unroll
    for (int cf = 0; cf < 8; ++cf)
#pragma unroll
      for (int r = 0; r < 4; ++r)
        Ps[wid][(l4 * 4 + r) * 136 + cf * 16 + l15] = f2bf(sf[cf][r]);
#pragma unroll
    for (int hf = 0; hf < 4; ++hf)
#pragma unroll
      for (int r = 0; r < 4; ++r) o[hf][r] *= fac[r];
    bf16x8 pa[4];
#pragma unroll
    for (int ks = 0; ks < 4; ++ks)
      pa[ks] = *(const bf16x8*)&Ps[wid][l15 * 136 + ks * 32 + l4 * 8];
#pragma unroll
    for (int hf = 0; hf < 4; ++hf) {
#pragma unroll
      for (int ks = 0; ks < 4; ++ks) {
        int P = (hf * 16 + l15) * 256 + (ks * 32 + l4 * 8) * 2;
        bf16x8 vb = *(const bf16x8*)((const char*)Vs + (P ^ (((P >> 8) & 7) << 4)));
        o[hf] = __builtin_amdgcn_mfma_f32_16x16x32_bf16(pa[ks], vb, o[hf], 0, 0, 0);
      }
    }
    __syncthreads();
  }
  float lsum[4];
#pragma unroll
  for (int r = 0; r < 4; ++r) {
    float s = l_part[r];
#pragma unroll
    for (int off = 1; off < 16; off <<= 1) s += __shfl_xor(s, off);
    lsum[r] = s;
  }
#pragma unroll
  for (int hf = 0; hf < 4; ++hf)
#pragma unroll
    for (int r = 0; r < 4; ++r) {
      float val = o[hf][r] / lsum[r];
      size_t row = (size_t)b * TTT + q0 + wid * 16 + l4 * 4 + r;
      attout[row * DD + nh * 64 + hf * 16 + l15] = f2bf(val);
    }
}

// ---------------- lm head: out[b][v] = dot(xlnf[b], wte[v]) fp32 ----------------
__global__ __launch_bounds__(256) void k_head(const float* __restrict__ xlnf,
                                              const float* __restrict__ wte,
                                              float* __restrict__ out) {
  __shared__ float xs[2 * DD];
  int tid = threadIdx.x;
#pragma unroll
  for (int i = 0; i < 2; ++i)
    *(float4*)(xs + i * DD + tid * 4) = *(const float4*)(xlnf + i * DD + tid * 4);
  __syncthreads();
  int wid = tid >> 6, lane = tid & 63;
  for (int v = blockIdx.x * 4 + wid; v < VVV; v += gridDim.x * 4) {
    const float* wr = wte + (size_t)v * DD;
    float a0 = 0.f, a1 = 0.f;
#pragma unroll
    for (int j = 0; j < 4; ++j) {
      const float4 wv = *(const float4*)(wr + lane * 16 + j * 4);
      const float4 x0 = *(const float4*)(xs + lane * 16 + j * 4);
      const float4 x1 = *(const float4*)(xs + DD + lane * 16 + j * 4);
      a0 += wv.x * x0.x + wv.y * x0.y + wv.z * x0.z + wv.w * x0.w;
      a1 += wv.x * x1.x + wv.y * x1.y + wv.z * x1.z + wv.w * x1.w;
    }
#pragma unroll
    for (int off = 1; off < 64; off <<= 1) { a0 += __shfl_xor(a0, off); a1 += __shfl_xor(a1, off); }
    if (lane == 0) { out[v] = a0; out[VVV + v] = a1; }
  }
}

extern "C" void kernel_launch(void* const* d_in, const int* in_sizes, int n_in,
                              void* d_out, int out_size, void* d_ws, size_t ws_size,
                              hipStream_t stream) {
  const int* tokens    = (const int*)d_in[0];
  const float* wte     = (const float*)d_in[1];
  const float* wpe     = (const float*)d_in[2];
  const float* ln1_w   = (const float*)d_in[3];
  const float* ln1_b   = (const float*)d_in[4];
  const float* attn_w  = (const float*)d_in[5];
  const float* attn_b  = (const float*)d_in[6];
  const float* aproj_w = (const float*)d_in[7];
  const float* aproj_b = (const float*)d_in[8];
  const float* ln2_w   = (const float*)d_in[9];
  const float* ln2_b   = (const float*)d_in[10];
  const float* fc_w    = (const float*)d_in[11];
  const float* fc_b    = (const float*)d_in[12];
  const float* proj_w  = (const float*)d_in[13];
  const float* proj_b  = (const float*)d_in[14];
  const float* lnf_w   = (const float*)d_in[15];
  const float* lnf_b   = (const float*)d_in[16];

  char* ws = (char*)d_ws;
  float* x    = (float*)(ws);                    // 8 MB
  u16* h      = (u16*)(ws + (8u << 20));         // 4 MB
  u16* qkv    = (u16*)(ws + (12u << 20));        // 12 MB
  u16* Kb     = (u16*)(ws + (24u << 20));        // 4 MB
  u16* Vt     = (u16*)(ws + (28u << 20));        // 4 MB
  u16* attb   = (u16*)(ws + (32u << 20));        // 4 MB
  u16* mlph   = (u16*)(ws + (36u << 20));        // 16 MB
  u16* wt     = (u16*)(ws + (52u << 20));        // 8 MB
  float* xlnf = (float*)(ws + (60u << 20));      // 8 KB
  float* out  = (float*)d_out;

  k_embed<<<MR, 256, 0, stream>>>(tokens, wte, wpe, x);

  for (int l = 0; l < 12; ++l) {
    k_ln<<<MR, 256, 0, stream>>>(x, ln1_w + l * DD, ln1_b + l * DD, h);
    k_wtrans<<<dim3(32, 96), 256, 0, stream>>>(attn_w + (size_t)l * DD * 3 * DD, wt, 1024, 3072);
    k_gemm<0><<<dim3(16, 24, 1), 256, 0, stream>>>(h, wt, attn_b + (size_t)l * 3 * DD, qkv, nullptr, MR, 3072, 1024, 1024);
    k_repack<<<dim3(128, 2), 256, 0, stream>>>(qkv, Kb, Vt);
    k_attn<<<dim3(32, 16), 256, 0, stream>>>(qkv, Kb, Vt, attb);
    k_wtrans<<<dim3(32, 32), 256, 0, stream>>>(aproj_w + (size_t)l * DD * DD, wt, 1024, 1024);
    k_gemm<3><<<dim3(16, 8, 2), 256, 0, stream>>>(attb, wt, aproj_b + (size_t)l * DD, nullptr, x, MR, 1024, 1024, 512);
    k_ln<<<MR, 256, 0, stream>>>(x, ln2_w + l * DD, ln2_b + l * DD, h);
    k_wtrans<<<dim3(32, 128), 256, 0, stream>>>(fc_w + (size_t)l * DD * FFF, wt, 1024, 4096);
    k_gemm<2><<<dim3(16, 32, 1), 256, 0, stream>>>(h, wt, fc_b + (size_t)l * FFF, mlph, nullptr, MR, 4096, 1024, 1024);
    k_wtrans<<<dim3(128, 32), 256, 0, stream>>>(proj_w + (size_t)l * FFF * DD, wt, 4096, 1024);
    k_gemm<3><<<dim3(16, 8, 4), 256, 0, stream>>>(mlph, wt, proj_b + (size_t)l * DD, nullptr, x, MR, 1024, 4096, 1024);
  }
  k_lnf<<<2, 256, 0, stream>>>(x, lnf_w, lnf_b, xlnf);
  k_head<<<512, 256, 0, stream>>>(xlnf, wte, out);
}

// Round 4
// 2271.111 us; speedup vs baseline: 1.4868x; 1.0555x over previous
//
#include <hip/hip_runtime.h>
#include <cstdint>
#include <math.h>

// GPT-2 forward, MI355X. B=2, T=1024, D=1024, NH=16, HD=64, L=12, F=4096, V=50257.
// fp32 residual; bf16 MFMA GEMMs (128^2 tile, 2-deep counted-vmcnt pipeline,
// raw s_barrier, setprio, XCD swizzle, split-K atomics); fused per-layer wtrans;
// flash attention 128-key tiles; fast-erf GELU.

using u16 = unsigned short;
using bf16x8 = __attribute__((ext_vector_type(8))) short;
using f32x4 = __attribute__((ext_vector_type(4))) float;

#define GLDS16(g, l)                                                        \
  __builtin_amdgcn_global_load_lds(                                         \
      (const __attribute__((address_space(1))) void*)(g),                   \
      (__attribute__((address_space(3))) void*)(l), 16, 0, 0)

__device__ __forceinline__ u16 f2bf(float f) {
  union { float f; unsigned u; } t; t.f = f;
  unsigned r = t.u + 0x7fffu + ((t.u >> 16) & 1u);
  return (u16)(r >> 16);
}

// A&S 7.1.26, |err| <= 1.5e-7
__device__ __forceinline__ float fast_erf(float x) {
  float ax = fabsf(x);
  float t = 1.f / (1.f + 0.3275911f * ax);
  float y = t * (0.254829592f +
            t * (-0.284496736f +
            t * (1.421413741f +
            t * (-1.453152027f +
            t * 1.061405429f))));
  float r = 1.f - y * __expf(-ax * ax);
  return copysignf(r, x);
}

#define DD 1024
#define TTT 1024
#define MR 2048     // B*T
#define FFF 4096
#define VVV 50257

// ---------------- embedding ----------------
__global__ __launch_bounds__(256) void k_embed(const int* __restrict__ tokens,
                                               const float* __restrict__ wte,
                                               const float* __restrict__ wpe,
                                               float* __restrict__ x) {
  int m = blockIdx.x, d = threadIdx.x * 4;
  int t = m & (TTT - 1);
  int tok = tokens[m];
  const float4 a = *(const float4*)(wte + (size_t)tok * DD + d);
  const float4 p = *(const float4*)(wpe + (size_t)t * DD + d);
  float4 o; o.x = a.x + p.x; o.y = a.y + p.y; o.z = a.z + p.z; o.w = a.w + p.w;
  *(float4*)(x + (size_t)m * DD + d) = o;
}

// ---------------- layernorm -> bf16 ----------------
__global__ __launch_bounds__(256) void k_ln(const float* __restrict__ x,
                                            const float* __restrict__ w,
                                            const float* __restrict__ b,
                                            u16* __restrict__ out) {
  int m = blockIdx.x, tid = threadIdx.x;
  const float4 v = *(const float4*)(x + (size_t)m * DD + tid * 4);
  float s = v.x + v.y + v.z + v.w;
  float q = v.x * v.x + v.y * v.y + v.z * v.z + v.w * v.w;
#pragma unroll
  for (int off = 1; off < 64; off <<= 1) { s += __shfl_xor(s, off); q += __shfl_xor(q, off); }
  __shared__ float sm[8];
  int wid = tid >> 6;
  if ((tid & 63) == 0) { sm[wid] = s; sm[4 + wid] = q; }
  __syncthreads();
  s = sm[0] + sm[1] + sm[2] + sm[3];
  q = sm[4] + sm[5] + sm[6] + sm[7];
  float mean = s * (1.f / DD);
  float var = q * (1.f / DD) - mean * mean;
  float rs = rsqrtf(var + 1e-5f);
  const float4 wv = *(const float4*)(w + tid * 4);
  const float4 bv = *(const float4*)(b + tid * 4);
  u16 o[4];
  o[0] = f2bf((v.x - mean) * rs * wv.x + bv.x);
  o[1] = f2bf((v.y - mean) * rs * wv.y + bv.y);
  o[2] = f2bf((v.z - mean) * rs * wv.z + bv.z);
  o[3] = f2bf((v.w - mean) * rs * wv.w + bv.w);
  *(uint64_t*)(out + (size_t)m * DD + tid * 4) = *(uint64_t*)o;
}

// final LN on the two last-token rows, fp32 out
__global__ __launch_bounds__(256) void k_lnf(const float* __restrict__ x,
                                             const float* __restrict__ w,
                                             const float* __restrict__ b,
                                             float* __restrict__ out) {
  int bb = blockIdx.x, tid = threadIdx.x;
  int m = bb * TTT + (TTT - 1);
  const float4 v = *(const float4*)(x + (size_t)m * DD + tid * 4);
  float s = v.x + v.y + v.z + v.w;
  float q = v.x * v.x + v.y * v.y + v.z * v.z + v.w * v.w;
#pragma unroll
  for (int off = 1; off < 64; off <<= 1) { s += __shfl_xor(s, off); q += __shfl_xor(q, off); }
  __shared__ float sm[8];
  int wid = tid >> 6;
  if ((tid & 63) == 0) { sm[wid] = s; sm[4 + wid] = q; }
  __syncthreads();
  s = sm[0] + sm[1] + sm[2] + sm[3];
  q = sm[4] + sm[5] + sm[6] + sm[7];
  float mean = s * (1.f / DD);
  float var = q * (1.f / DD) - mean * mean;
  float rs = rsqrtf(var + 1e-5f);
  const float4 wv = *(const float4*)(w + tid * 4);
  const float4 bv = *(const float4*)(b + tid * 4);
  float4 o;
  o.x = (v.x - mean) * rs * wv.x + bv.x;
  o.y = (v.y - mean) * rs * wv.y + bv.y;
  o.z = (v.z - mean) * rs * wv.z + bv.z;
  o.w = (v.w - mean) * rs * wv.w + bv.w;
  *(float4*)(out + (size_t)bb * DD + tid * 4) = o;
}

// ---------------- fused weight transpose: all 4 matrices of one layer ----------------
// fp32 [K,N] -> bf16 [N,K]; wt layout: atw@0, apw@3145728, fcw@4194304, pjw@8388608
__global__ __launch_bounds__(256) void k_wtrans_all(const float* __restrict__ atw_s,
                                                    const float* __restrict__ apw_s,
                                                    const float* __restrict__ fcw_s,
                                                    const float* __restrict__ pjw_s,
                                                    u16* __restrict__ wt) {
  __shared__ float tile[32][33];
  int id = blockIdx.x;
  const float* W; u16* Wt; int K, N, local, kts;
  if (id < 3072)      { W = atw_s; Wt = wt;           K = 1024; N = 3072; local = id;        kts = 5; }
  else if (id < 4096) { W = apw_s; Wt = wt + 3145728; K = 1024; N = 1024; local = id - 3072; kts = 5; }
  else if (id < 8192) { W = fcw_s; Wt = wt + 4194304; K = 1024; N = 4096; local = id - 4096; kts = 5; }
  else                { W = pjw_s; Wt = wt + 8388608; K = 4096; N = 1024; local = id - 8192; kts = 7; }
  int k0 = (local & ((1 << kts) - 1)) * 32, n0 = (local >> kts) * 32;
  int tx = threadIdx.x & 31, ty = threadIdx.x >> 5;  // ty in [0,8)
#pragma unroll
  for (int i = 0; i < 4; ++i)
    tile[ty + i * 8][tx] = W[(size_t)(k0 + ty + i * 8) * N + n0 + tx];
  __syncthreads();
#pragma unroll
  for (int i = 0; i < 4; ++i)
    Wt[(size_t)(n0 + ty + i * 8) * K + k0 + tx] = f2bf(tile[tx][ty + i * 8]);
}

// ---------------- GEMM: out = A[M,K] * Bt[N,K]^T + bias ----------------
// 2-deep pipeline with counted vmcnt: STAGE(t+1) issued, then s_waitcnt vmcnt(8)
// (buf[t] ready, buf[t+1] stays in flight across the barrier), raw s_barrier.
// EPI 0: bf16 out; EPI 2: gelu->bf16; EPI 3: atomicAdd xres (split-K, bias bz==0).
template <int EPI>
__global__ __launch_bounds__(256) void k_gemm(const u16* __restrict__ A,
                                              const u16* __restrict__ Bt,
                                              const float* __restrict__ bias,
                                              u16* __restrict__ outb,
                                              float* __restrict__ xres,
                                              int M, int N, int K, int KC) {
  __shared__ u16 As[2][128 * 64];
  __shared__ u16 Bs[2][128 * 64];
  // bijective XCD swizzle (m204)
  const int nbx = gridDim.x, nby = gridDim.y;
  const int nwg = nbx * nby * gridDim.z;
  const int orig = blockIdx.x + nbx * (blockIdx.y + nby * blockIdx.z);
  const int qq = nwg >> 3, rr = nwg & 7;
  const int xcd = orig & 7, pos = orig >> 3;
  const int wg = (xcd < rr ? xcd * (qq + 1) : rr * (qq + 1) + (xcd - rr) * qq) + pos;
  const int bx = wg % nbx;
  const int tmpw = wg / nbx;
  const int by = tmpw % nby, bz = tmpw / nby;

  const int tid = threadIdx.x;
  const int lane = tid & 63, wid = tid >> 6;
  const int wr = wid >> 1, wc = wid & 1;
  const int l15 = lane & 15, l4 = lane >> 4;
  const int m0 = bx * 128, n0 = by * 128;
  f32x4 acc[4][4] = {};

  const int srow = tid >> 3, scol = (tid & 7) * 8;
  const int k0beg = bz * KC;
  const int nt = KC >> 6;

  const u16* Ap = A + (size_t)(m0 + srow) * K + scol;
  const u16* Bp = Bt + (size_t)(n0 + srow) * K + scol;

#define STAGE(buf, k0)                                                      \
  {                                                                         \
    _Pragma("unroll")                                                       \
    for (int it = 0; it < 4; ++it) {                                        \
      GLDS16(Ap + (size_t)it * 32 * K + (k0), (char*)As[buf] + it * 4096 + tid * 16); \
      GLDS16(Bp + (size_t)it * 32 * K + (k0), (char*)Bs[buf] + it * 4096 + tid * 16); \
    }                                                                       \
  }

  STAGE(0, k0beg);
  for (int t = 0; t < nt; ++t) {
    if (t + 1 < nt) {
      STAGE((t + 1) & 1, k0beg + (t + 1) * 64);
      asm volatile("s_waitcnt vmcnt(8)" ::: "memory");
    } else {
      asm volatile("s_waitcnt vmcnt(0)" ::: "memory");
    }
    __builtin_amdgcn_sched_barrier(0);
    __builtin_amdgcn_s_barrier();
    __builtin_amdgcn_sched_barrier(0);
    const u16* Ab = As[t & 1];
    const u16* Bb = Bs[t & 1];
#pragma unroll
    for (int ks = 0; ks < 2; ++ks) {
      bf16x8 af[4], bfr[4];
#pragma unroll
      for (int i = 0; i < 4; ++i)
        af[i] = *(const bf16x8*)(Ab + (wr * 64 + i * 16 + l15) * 64 + ks * 32 + l4 * 8);
#pragma unroll
      for (int j = 0; j < 4; ++j)
        bfr[j] = *(const bf16x8*)(Bb + (wc * 64 + j * 16 + l15) * 64 + ks * 32 + l4 * 8);
      __builtin_amdgcn_s_setprio(1);
#pragma unroll
      for (int i = 0; i < 4; ++i)
#pragma unroll
        for (int j = 0; j < 4; ++j)
          acc[i][j] = __builtin_amdgcn_mfma_f32_16x16x32_bf16(af[i], bfr[j], acc[i][j], 0, 0, 0);
      __builtin_amdgcn_s_setprio(0);
    }
    __builtin_amdgcn_sched_barrier(0);
    __builtin_amdgcn_s_barrier();
    __builtin_amdgcn_sched_barrier(0);
  }
#undef STAGE
#pragma unroll
  for (int j = 0; j < 4; ++j) {
    const int col = n0 + wc * 64 + j * 16 + l15;
    const float bs = (EPI == 3 && bz != 0) ? 0.f : bias[col];
#pragma unroll
    for (int i = 0; i < 4; ++i) {
#pragma unroll
      for (int r = 0; r < 4; ++r) {
        const int row = m0 + wr * 64 + i * 16 + l4 * 4 + r;
        float v = acc[i][j][r] + bs;
        if (EPI == 0) {
          outb[(size_t)row * N + col] = f2bf(v);
        } else if (EPI == 2) {
          float g = 0.5f * v * (1.f + fast_erf(v * 0.70710678118f));
          outb[(size_t)row * N + col] = f2bf(g);
        } else {
          atomicAdd(&xres[(size_t)row * N + col], v);
        }
      }
    }
  }
}

// ---------------- K/V repack via LDS de-interleave ----------------
// qkv col d = h*16 + n (head n, dim h). K -> Kb[bn][t][h]; V -> Vt[bn][h][t].
__global__ __launch_bounds__(256) void k_repack(const u16* __restrict__ qkv,
                                                u16* __restrict__ Kb,
                                                u16* __restrict__ Vt) {
  __shared__ u16 tile[16 * 1024];
  const int tid = threadIdx.x;
  const int m0 = blockIdx.x * 16;
  const int part = blockIdx.y + 1;     // 1=K, 2=V
  const int b = m0 >> 10;
  const int tg0 = m0 & (TTT - 1);
#pragma unroll
  for (int p = 0; p < 8; ++p) {
    int row = p * 2 + (tid >> 7);
    int col8 = (tid & 127) * 8;
    bf16x8 v = *(const bf16x8*)(qkv + (size_t)(m0 + row) * 3072 + part * 1024 + col8);
    int e = col8 ^ (((col8 >> 4) & 7) << 3);
    *(bf16x8*)(tile + row * 1024 + e) = v;
  }
  __syncthreads();
  const int lane = tid & 63, wid = tid >> 6;
  if (part == 1) {
    for (int p = wid; p < 256; p += 4) {
      int t = p >> 4, n = p & 15;
      int e = (lane * 16 + n) ^ ((lane & 7) << 3);
      u16 val = tile[t * 1024 + e];
      Kb[(((size_t)(b * 16 + n)) * TTT + tg0 + t) * 64 + lane] = val;
    }
  } else {
    for (int p = wid; p < 32; p += 4) {
      int n = p >> 1, tc = p & 1;
      int e = (lane * 16 + n) ^ ((lane & 7) << 3);
      u16 val8[8];
#pragma unroll
      for (int k = 0; k < 8; ++k) val8[k] = tile[(tc * 8 + k) * 1024 + e];
      *(bf16x8*)(Vt + (((size_t)(b * 16 + n)) * 64 + lane) * TTT + tg0 + tc * 8) =
          *(bf16x8*)val8;
    }
  }
}

// ---------------- flash attention (causal), 64 q-rows, 128-key tiles ----------------
__global__ __launch_bounds__(256) void k_attn(const u16* __restrict__ qkv,
                                              const u16* __restrict__ Kb,
                                              const u16* __restrict__ Vt,
                                              u16* __restrict__ attout) {
  __shared__ u16 Ks[128 * 64];
  __shared__ u16 Vs[64 * 128];
  __shared__ u16 Ps[4][16 * 136];

  const int tid = threadIdx.x;
  const int lane = tid & 63, wid = tid >> 6;
  const int l15 = lane & 15, l4 = lane >> 4;
  const int bn = blockIdx.x;                 // b*16 + n
  const int qtr = 15 - (int)blockIdx.y;      // heavy tiles first
  const int q0 = qtr * 64;
  const int b = bn >> 4, nh = bn & 15;

  const int qrow = q0 + wid * 16 + l15;
  const u16* qsrc = qkv + (size_t)(b * TTT + qrow) * 3072 + nh;
  bf16x8 aq[2];
#pragma unroll
  for (int ks = 0; ks < 2; ++ks) {
    short tmp[8];
#pragma unroll
    for (int j = 0; j < 8; ++j) tmp[j] = (short)qsrc[(ks * 32 + l4 * 8 + j) * 16];
    aq[ks] = *(bf16x8*)tmp;
  }

  const char* Kg0 = (const char*)(Kb + (size_t)bn * TTT * 64);
  const char* Vg0 = (const char*)(Vt + (size_t)bn * 64 * TTT);

  float m_run[4], l_part[4];
  f32x4 o[4] = {};
#pragma unroll
  for (int r = 0; r < 4; ++r) { m_run[r] = -1e30f; l_part[r] = 0.f; }

  const int ntk = (qtr >> 1) + 1;
  for (int kt = 0; kt < ntk; ++kt) {
#pragma unroll
    for (int it = 0; it < 4; ++it) {
      int L = it * 4096 + tid * 16;
      int Ls = L ^ (((L >> 7) & 7) << 4);
      GLDS16(Kg0 + (size_t)kt * 16384 + Ls, (char*)Ks + L);
    }
#pragma unroll
    for (int it = 0; it < 4; ++it) {
      int L = it * 4096 + tid * 16;
      int Ls = L ^ (((L >> 8) & 7) << 4);
      int hrow = Ls >> 8, cb = Ls & 255;
      GLDS16(Vg0 + (size_t)hrow * 2048 + kt * 256 + cb, (char*)Vs + L);
    }
    __syncthreads();

    f32x4 sf[8];
#pragma unroll
    for (int cf = 0; cf < 8; ++cf) {
      f32x4 z = {};
#pragma unroll
      for (int ks = 0; ks < 2; ++ks) {
        int P = (cf * 16 + l15) * 128 + (ks * 32 + l4 * 8) * 2;
        bf16x8 kb = *(const bf16x8*)((const char*)Ks + (P ^ (((P >> 7) & 7) << 4)));
        z = __builtin_amdgcn_mfma_f32_16x16x32_bf16(aq[ks], kb, z, 0, 0, 0);
      }
      sf[cf] = z;
    }
    const bool lastkt = (kt == ntk - 1);
#pragma unroll
    for (int cf = 0; cf < 8; ++cf)
#pragma unroll
      for (int r = 0; r < 4; ++r) {
        float s = sf[cf][r] * 0.125f;
        if (lastkt) {
          int kg = kt * 128 + cf * 16 + l15;
          int qg = q0 + wid * 16 + l4 * 4 + r;
          if (kg > qg) s = -1e30f;
        }
        sf[cf][r] = s;
      }
    float fac[4];
#pragma unroll
    for (int r = 0; r < 4; ++r) {
      float tm = sf[0][r];
#pragma unroll
      for (int cf = 1; cf < 8; ++cf) tm = fmaxf(tm, sf[cf][r]);
#pragma unroll
      for (int off = 1; off < 16; off <<= 1) tm = fmaxf(tm, __shfl_xor(tm, off));
      float mnew = fmaxf(m_run[r], tm);
      fac[r] = __expf(m_run[r] - mnew);
      m_run[r] = mnew;
      float ps = 0.f;
#pragma unroll
      for (int cf = 0; cf < 8; ++cf) {
        float p = __expf(sf[cf][r] - mnew);
        sf[cf][r] = p;
        ps += p;
      }
      l_part[r] = l_part[r] * fac[r] + ps;
    }
#pragma unroll
    for (int cf = 0; cf < 8; ++cf)
#pragma unroll
      for (int r = 0; r < 4; ++r)
        Ps[wid][(l4 * 4 + r) * 136 + cf * 16 + l15] = f2bf(sf[cf][r]);
#pragma unroll
    for (int hf = 0; hf < 4; ++hf)
#pragma unroll
      for (int r = 0; r < 4; ++r) o[hf][r] *= fac[r];
    bf16x8 pa[4];
#pragma unroll
    for (int ks = 0; ks < 4; ++ks)
      pa[ks] = *(const bf16x8*)&Ps[wid][l15 * 136 + ks * 32 + l4 * 8];
#pragma unroll
    for (int hf = 0; hf < 4; ++hf) {
#pragma unroll
      for (int ks = 0; ks < 4; ++ks) {
        int P = (hf * 16 + l15) * 256 + (ks * 32 + l4 * 8) * 2;
        bf16x8 vb = *(const bf16x8*)((const char*)Vs + (P ^ (((P >> 8) & 7) << 4)));
        o[hf] = __builtin_amdgcn_mfma_f32_16x16x32_bf16(pa[ks], vb, o[hf], 0, 0, 0);
      }
    }
    __syncthreads();
  }
  float lsum[4];
#pragma unroll
  for (int r = 0; r < 4; ++r) {
    float s = l_part[r];
#pragma unroll
    for (int off = 1; off < 16; off <<= 1) s += __shfl_xor(s, off);
    lsum[r] = s;
  }
#pragma unroll
  for (int hf = 0; hf < 4; ++hf)
#pragma unroll
    for (int r = 0; r < 4; ++r) {
      float val = o[hf][r] / lsum[r];
      size_t row = (size_t)b * TTT + q0 + wid * 16 + l4 * 4 + r;
      attout[row * DD + nh * 64 + hf * 16 + l15] = f2bf(val);
    }
}

// ---------------- lm head: out[b][v] = dot(xlnf[b], wte[v]) fp32 ----------------
__global__ __launch_bounds__(256) void k_head(const float* __restrict__ xlnf,
                                              const float* __restrict__ wte,
                                              float* __restrict__ out) {
  __shared__ float xs[2 * DD];
  int tid = threadIdx.x;
#pragma unroll
  for (int i = 0; i < 2; ++i)
    *(float4*)(xs + i * DD + tid * 4) = *(const float4*)(xlnf + i * DD + tid * 4);
  __syncthreads();
  int wid = tid >> 6, lane = tid & 63;
  for (int v = blockIdx.x * 4 + wid; v < VVV; v += gridDim.x * 4) {
    const float* wr = wte + (size_t)v * DD;
    float a0 = 0.f, a1 = 0.f;
#pragma unroll
    for (int j = 0; j < 4; ++j) {
      const float4 wv = *(const float4*)(wr + lane * 16 + j * 4);
      const float4 x0 = *(const float4*)(xs + lane * 16 + j * 4);
      const float4 x1 = *(const float4*)(xs + DD + lane * 16 + j * 4);
      a0 += wv.x * x0.x + wv.y * x0.y + wv.z * x0.z + wv.w * x0.w;
      a1 += wv.x * x1.x + wv.y * x1.y + wv.z * x1.z + wv.w * x1.w;
    }
#pragma unroll
    for (int off = 1; off < 64; off <<= 1) { a0 += __shfl_xor(a0, off); a1 += __shfl_xor(a1, off); }
    if (lane == 0) { out[v] = a0; out[VVV + v] = a1; }
  }
}

extern "C" void kernel_launch(void* const* d_in, const int* in_sizes, int n_in,
                              void* d_out, int out_size, void* d_ws, size_t ws_size,
                              hipStream_t stream) {
  const int* tokens    = (const int*)d_in[0];
  const float* wte     = (const float*)d_in[1];
  const float* wpe     = (const float*)d_in[2];
  const float* ln1_w   = (const float*)d_in[3];
  const float* ln1_b   = (const float*)d_in[4];
  const float* attn_w  = (const float*)d_in[5];
  const float* attn_b  = (const float*)d_in[6];
  const float* aproj_w = (const float*)d_in[7];
  const float* aproj_b = (const float*)d_in[8];
  const float* ln2_w   = (const float*)d_in[9];
  const float* ln2_b   = (const float*)d_in[10];
  const float* fc_w    = (const float*)d_in[11];
  const float* fc_b    = (const float*)d_in[12];
  const float* proj_w  = (const float*)d_in[13];
  const float* proj_b  = (const float*)d_in[14];
  const float* lnf_w   = (const float*)d_in[15];
  const float* lnf_b   = (const float*)d_in[16];

  char* ws = (char*)d_ws;
  float* x    = (float*)(ws);                    // 0..8 MiB
  u16* h      = (u16*)(ws + (8u << 20));         // 8..12
  u16* wt     = (u16*)(ws + (12u << 20));        // 12..36 (atw/apw/fcw/pjw)
  u16* qkv    = (u16*)(ws + (36u << 20));        // 36..48
  u16* Kb     = (u16*)(ws + (48u << 20));        // 48..52
  u16* Vt     = (u16*)(ws + (52u << 20));        // 52..56
  u16* attb   = (u16*)(ws + (56u << 20));        // 56..60
  u16* mlph   = (u16*)(ws + (36u << 20));        // 36..52 (aliases dead qkv/Kb)
  float* xlnf = (float*)(ws + (60u << 20));      // 60 MiB + 8 KB
  float* out  = (float*)d_out;

  u16* atw = wt;
  u16* apw = wt + 3145728;
  u16* fcw = wt + 4194304;
  u16* pjw = wt + 8388608;

  k_embed<<<MR, 256, 0, stream>>>(tokens, wte, wpe, x);

  for (int l = 0; l < 12; ++l) {
    k_wtrans_all<<<12288, 256, 0, stream>>>(attn_w + (size_t)l * DD * 3 * DD,
                                            aproj_w + (size_t)l * DD * DD,
                                            fc_w + (size_t)l * DD * FFF,
                                            proj_w + (size_t)l * FFF * DD, wt);
    k_ln<<<MR, 256, 0, stream>>>(x, ln1_w + l * DD, ln1_b + l * DD, h);
    k_gemm<0><<<dim3(16, 24, 1), 256, 0, stream>>>(h, atw, attn_b + (size_t)l * 3 * DD, qkv, nullptr, MR, 3072, 1024, 1024);
    k_repack<<<dim3(128, 2), 256, 0, stream>>>(qkv, Kb, Vt);
    k_attn<<<dim3(32, 16), 256, 0, stream>>>(qkv, Kb, Vt, attb);
    k_gemm<3><<<dim3(16, 8, 2), 256, 0, stream>>>(attb, apw, aproj_b + (size_t)l * DD, nullptr, x, MR, 1024, 1024, 512);
    k_ln<<<MR, 256, 0, stream>>>(x, ln2_w + l * DD, ln2_b + l * DD, h);
    k_gemm<2><<<dim3(16, 32, 1), 256, 0, stream>>>(h, fcw, fc_b + (size_t)l * FFF, mlph, nullptr, MR, 4096, 1024, 1024);
    k_gemm<3><<<dim3(16, 8, 4), 256, 0, stream>>>(mlph, pjw, proj_b + (size_t)l * DD, nullptr, x, MR, 1024, 4096, 1024);
  }
  k_lnf<<<2, 256, 0, stream>>>(x, lnf_w, lnf_b, xlnf);
  k_head<<<512, 256, 0, stream>>>(xlnf, wte, out);
}

// Round 5
// 2154.324 us; speedup vs baseline: 1.5674x; 1.0542x over previous
//
#include <hip/hip_runtime.h>
#include <cstdint>
#include <math.h>

// GPT-2 forward, MI355X. B=2, T=1024, D=1024, NH=16, HD=64, L=12, F=4096, V=50257.
// fp32 residual; bf16 MFMA GEMMs (128^2 tile, 2-deep counted-vmcnt pipeline,
// 3-bit XOR LDS swizzle (T2), raw s_barrier, setprio, XCD swizzle, split-K);
// fused per-layer wtrans; balanced flash attention; fast-erf GELU.

using u16 = unsigned short;
using bf16x8 = __attribute__((ext_vector_type(8))) short;
using f32x4 = __attribute__((ext_vector_type(4))) float;

#define GLDS16(g, l)                                                        \
  __builtin_amdgcn_global_load_lds(                                         \
      (const __attribute__((address_space(1))) void*)(g),                   \
      (__attribute__((address_space(3))) void*)(l), 16, 0, 0)

__device__ __forceinline__ u16 f2bf(float f) {
  union { float f; unsigned u; } t; t.f = f;
  unsigned r = t.u + 0x7fffu + ((t.u >> 16) & 1u);
  return (u16)(r >> 16);
}

// A&S 7.1.26, |err| <= 1.5e-7
__device__ __forceinline__ float fast_erf(float x) {
  float ax = fabsf(x);
  float t = 1.f / (1.f + 0.3275911f * ax);
  float y = t * (0.254829592f +
            t * (-0.284496736f +
            t * (1.421413741f +
            t * (-1.453152027f +
            t * 1.061405429f))));
  float r = 1.f - y * __expf(-ax * ax);
  return copysignf(r, x);
}

#define DD 1024
#define TTT 1024
#define MR 2048     // B*T
#define FFF 4096
#define VVV 50257

// ---------------- embedding ----------------
__global__ __launch_bounds__(256) void k_embed(const int* __restrict__ tokens,
                                               const float* __restrict__ wte,
                                               const float* __restrict__ wpe,
                                               float* __restrict__ x) {
  int m = blockIdx.x, d = threadIdx.x * 4;
  int t = m & (TTT - 1);
  int tok = tokens[m];
  const float4 a = *(const float4*)(wte + (size_t)tok * DD + d);
  const float4 p = *(const float4*)(wpe + (size_t)t * DD + d);
  float4 o; o.x = a.x + p.x; o.y = a.y + p.y; o.z = a.z + p.z; o.w = a.w + p.w;
  *(float4*)(x + (size_t)m * DD + d) = o;
}

// ---------------- layernorm -> bf16 ----------------
__global__ __launch_bounds__(256) void k_ln(const float* __restrict__ x,
                                            const float* __restrict__ w,
                                            const float* __restrict__ b,
                                            u16* __restrict__ out) {
  int m = blockIdx.x, tid = threadIdx.x;
  const float4 v = *(const float4*)(x + (size_t)m * DD + tid * 4);
  float s = v.x + v.y + v.z + v.w;
  float q = v.x * v.x + v.y * v.y + v.z * v.z + v.w * v.w;
#pragma unroll
  for (int off = 1; off < 64; off <<= 1) { s += __shfl_xor(s, off); q += __shfl_xor(q, off); }
  __shared__ float sm[8];
  int wid = tid >> 6;
  if ((tid & 63) == 0) { sm[wid] = s; sm[4 + wid] = q; }
  __syncthreads();
  s = sm[0] + sm[1] + sm[2] + sm[3];
  q = sm[4] + sm[5] + sm[6] + sm[7];
  float mean = s * (1.f / DD);
  float var = q * (1.f / DD) - mean * mean;
  float rs = rsqrtf(var + 1e-5f);
  const float4 wv = *(const float4*)(w + tid * 4);
  const float4 bv = *(const float4*)(b + tid * 4);
  u16 o[4];
  o[0] = f2bf((v.x - mean) * rs * wv.x + bv.x);
  o[1] = f2bf((v.y - mean) * rs * wv.y + bv.y);
  o[2] = f2bf((v.z - mean) * rs * wv.z + bv.z);
  o[3] = f2bf((v.w - mean) * rs * wv.w + bv.w);
  *(uint64_t*)(out + (size_t)m * DD + tid * 4) = *(uint64_t*)o;
}

// final LN on the two last-token rows, fp32 out
__global__ __launch_bounds__(256) void k_lnf(const float* __restrict__ x,
                                             const float* __restrict__ w,
                                             const float* __restrict__ b,
                                             float* __restrict__ out) {
  int bb = blockIdx.x, tid = threadIdx.x;
  int m = bb * TTT + (TTT - 1);
  const float4 v = *(const float4*)(x + (size_t)m * DD + tid * 4);
  float s = v.x + v.y + v.z + v.w;
  float q = v.x * v.x + v.y * v.y + v.z * v.z + v.w * v.w;
#pragma unroll
  for (int off = 1; off < 64; off <<= 1) { s += __shfl_xor(s, off); q += __shfl_xor(q, off); }
  __shared__ float sm[8];
  int wid = tid >> 6;
  if ((tid & 63) == 0) { sm[wid] = s; sm[4 + wid] = q; }
  __syncthreads();
  s = sm[0] + sm[1] + sm[2] + sm[3];
  q = sm[4] + sm[5] + sm[6] + sm[7];
  float mean = s * (1.f / DD);
  float var = q * (1.f / DD) - mean * mean;
  float rs = rsqrtf(var + 1e-5f);
  const float4 wv = *(const float4*)(w + tid * 4);
  const float4 bv = *(const float4*)(b + tid * 4);
  float4 o;
  o.x = (v.x - mean) * rs * wv.x + bv.x;
  o.y = (v.y - mean) * rs * wv.y + bv.y;
  o.z = (v.z - mean) * rs * wv.z + bv.z;
  o.w = (v.w - mean) * rs * wv.w + bv.w;
  *(float4*)(out + (size_t)bb * DD + tid * 4) = o;
}

// ---------------- fused weight transpose: all 4 matrices of one layer ----------------
__global__ __launch_bounds__(256) void k_wtrans_all(const float* __restrict__ atw_s,
                                                    const float* __restrict__ apw_s,
                                                    const float* __restrict__ fcw_s,
                                                    const float* __restrict__ pjw_s,
                                                    u16* __restrict__ wt) {
  __shared__ float tile[32][33];
  int id = blockIdx.x;
  const float* W; u16* Wt; int K, N, local, kts;
  if (id < 3072)      { W = atw_s; Wt = wt;           K = 1024; N = 3072; local = id;        kts = 5; }
  else if (id < 4096) { W = apw_s; Wt = wt + 3145728; K = 1024; N = 1024; local = id - 3072; kts = 5; }
  else if (id < 8192) { W = fcw_s; Wt = wt + 4194304; K = 1024; N = 4096; local = id - 4096; kts = 5; }
  else                { W = pjw_s; Wt = wt + 8388608; K = 4096; N = 1024; local = id - 8192; kts = 7; }
  int k0 = (local & ((1 << kts) - 1)) * 32, n0 = (local >> kts) * 32;
  int tx = threadIdx.x & 31, ty = threadIdx.x >> 5;  // ty in [0,8)
#pragma unroll
  for (int i = 0; i < 4; ++i)
    tile[ty + i * 8][tx] = W[(size_t)(k0 + ty + i * 8) * N + n0 + tx];
  __syncthreads();
#pragma unroll
  for (int i = 0; i < 4; ++i)
    Wt[(size_t)(n0 + ty + i * 8) * K + k0 + tx] = f2bf(tile[tx][ty + i * 8]);
}

// ---------------- GEMM: out = A[M,K] * Bt[N,K]^T + bias ----------------
// 2-deep counted-vmcnt pipeline + 3-bit XOR LDS swizzle:
//   phys 16B-chunk p of row r holds logical chunk p ^ (r&7); staging applies the
//   inverse on the global source column, frag reads XOR the chunk index.
// EPI 0: bf16 out; EPI 2: gelu->bf16; EPI 3: atomicAdd xres (split-K, bias bz==0).
template <int EPI>
__global__ __launch_bounds__(256) void k_gemm(const u16* __restrict__ A,
                                              const u16* __restrict__ Bt,
                                              const float* __restrict__ bias,
                                              u16* __restrict__ outb,
                                              float* __restrict__ xres,
                                              int M, int N, int K, int KC) {
  __shared__ u16 As[2][128 * 64];
  __shared__ u16 Bs[2][128 * 64];
  // bijective XCD swizzle (m204)
  const int nbx = gridDim.x, nby = gridDim.y;
  const int nwg = nbx * nby * gridDim.z;
  const int orig = blockIdx.x + nbx * (blockIdx.y + nby * blockIdx.z);
  const int qq = nwg >> 3, rr = nwg & 7;
  const int xcd = orig & 7, pos = orig >> 3;
  const int wg = (xcd < rr ? xcd * (qq + 1) : rr * (qq + 1) + (xcd - rr) * qq) + pos;
  const int bx = wg % nbx;
  const int tmpw = wg / nbx;
  const int by = tmpw % nby, bz = tmpw / nby;

  const int tid = threadIdx.x;
  const int lane = tid & 63, wid = tid >> 6;
  const int wr = wid >> 1, wc = wid & 1;
  const int l15 = lane & 15, l4 = lane >> 4;
  const int sx = l15 & 7;              // row&7 for all frag rows (rows ≡ l15 mod 8)
  const int m0 = bx * 128, n0 = by * 128;
  f32x4 acc[4][4] = {};

  const int srow = tid >> 3;
  const int scol = (((tid & 7) ^ ((tid >> 3) & 7)) * 8);  // inverse swizzle on source
  const int k0beg = bz * KC;
  const int nt = KC >> 6;

  const u16* Ap = A + (size_t)(m0 + srow) * K + scol;
  const u16* Bp = Bt + (size_t)(n0 + srow) * K + scol;

#define STAGE(buf, k0)                                                      \
  {                                                                         \
    _Pragma("unroll")                                                       \
    for (int it = 0; it < 4; ++it) {                                        \
      GLDS16(Ap + (size_t)it * 32 * K + (k0), (char*)As[buf] + it * 4096 + tid * 16); \
      GLDS16(Bp + (size_t)it * 32 * K + (k0), (char*)Bs[buf] + it * 4096 + tid * 16); \
    }                                                                       \
  }

  STAGE(0, k0beg);
  for (int t = 0; t < nt; ++t) {
    if (t + 1 < nt) {
      STAGE((t + 1) & 1, k0beg + (t + 1) * 64);
      asm volatile("s_waitcnt vmcnt(8)" ::: "memory");
    } else {
      asm volatile("s_waitcnt vmcnt(0)" ::: "memory");
    }
    __builtin_amdgcn_sched_barrier(0);
    __builtin_amdgcn_s_barrier();
    __builtin_amdgcn_sched_barrier(0);
    const u16* Ab = As[t & 1];
    const u16* Bb = Bs[t & 1];
#pragma unroll
    for (int ks = 0; ks < 2; ++ks) {
      const int ch = ((ks * 4 + l4) ^ sx) * 8;   // swizzled chunk offset (elems)
      bf16x8 af[4], bfr[4];
#pragma unroll
      for (int i = 0; i < 4; ++i)
        af[i] = *(const bf16x8*)(Ab + (wr * 64 + i * 16 + l15) * 64 + ch);
#pragma unroll
      for (int j = 0; j < 4; ++j)
        bfr[j] = *(const bf16x8*)(Bb + (wc * 64 + j * 16 + l15) * 64 + ch);
      __builtin_amdgcn_s_setprio(1);
#pragma unroll
      for (int i = 0; i < 4; ++i)
#pragma unroll
        for (int j = 0; j < 4; ++j)
          acc[i][j] = __builtin_amdgcn_mfma_f32_16x16x32_bf16(af[i], bfr[j], acc[i][j], 0, 0, 0);
      __builtin_amdgcn_s_setprio(0);
    }
    __builtin_amdgcn_sched_barrier(0);
    __builtin_amdgcn_s_barrier();
    __builtin_amdgcn_sched_barrier(0);
  }
#undef STAGE
#pragma unroll
  for (int j = 0; j < 4; ++j) {
    const int col = n0 + wc * 64 + j * 16 + l15;
    const float bs = (EPI == 3 && bz != 0) ? 0.f : bias[col];
#pragma unroll
    for (int i = 0; i < 4; ++i) {
#pragma unroll
      for (int r = 0; r < 4; ++r) {
        const int row = m0 + wr * 64 + i * 16 + l4 * 4 + r;
        float v = acc[i][j][r] + bs;
        if (EPI == 0) {
          outb[(size_t)row * N + col] = f2bf(v);
        } else if (EPI == 2) {
          float g = 0.5f * v * (1.f + fast_erf(v * 0.70710678118f));
          outb[(size_t)row * N + col] = f2bf(g);
        } else {
          atomicAdd(&xres[(size_t)row * N + col], v);
        }
      }
    }
  }
}

// ---------------- K/V repack via LDS de-interleave ----------------
__global__ __launch_bounds__(256) void k_repack(const u16* __restrict__ qkv,
                                                u16* __restrict__ Kb,
                                                u16* __restrict__ Vt) {
  __shared__ u16 tile[16 * 1024];
  const int tid = threadIdx.x;
  const int m0 = blockIdx.x * 16;
  const int part = blockIdx.y + 1;     // 1=K, 2=V
  const int b = m0 >> 10;
  const int tg0 = m0 & (TTT - 1);
#pragma unroll
  for (int p = 0; p < 8; ++p) {
    int row = p * 2 + (tid >> 7);
    int col8 = (tid & 127) * 8;
    bf16x8 v = *(const bf16x8*)(qkv + (size_t)(m0 + row) * 3072 + part * 1024 + col8);
    int e = col8 ^ (((col8 >> 4) & 7) << 3);
    *(bf16x8*)(tile + row * 1024 + e) = v;
  }
  __syncthreads();
  const int lane = tid & 63, wid = tid >> 6;
  if (part == 1) {
    for (int p = wid; p < 256; p += 4) {
      int t = p >> 4, n = p & 15;
      int e = (lane * 16 + n) ^ ((lane & 7) << 3);
      u16 val = tile[t * 1024 + e];
      Kb[(((size_t)(b * 16 + n)) * TTT + tg0 + t) * 64 + lane] = val;
    }
  } else {
    for (int p = wid; p < 32; p += 4) {
      int n = p >> 1, tc = p & 1;
      int e = (lane * 16 + n) ^ ((lane & 7) << 3);
      u16 val8[8];
#pragma unroll
      for (int k = 0; k < 8; ++k) val8[k] = tile[(tc * 8 + k) * 1024 + e];
      *(bf16x8*)(Vt + (((size_t)(b * 16 + n)) * 64 + lane) * TTT + tg0 + tc * 8) =
          *(bf16x8*)val8;
    }
  }
}

// ---------------- flash attention (causal), balanced: block = qtile pair ----------------
__global__ __launch_bounds__(256) void k_attn(const u16* __restrict__ qkv,
                                              const u16* __restrict__ Kb,
                                              const u16* __restrict__ Vt,
                                              u16* __restrict__ attout) {
  __shared__ u16 Ks[128 * 64];
  __shared__ u16 Vs[64 * 128];
  __shared__ u16 Ps[4][16 * 136];

  const int tid = threadIdx.x;
  const int lane = tid & 63, wid = tid >> 6;
  const int l15 = lane & 15, l4 = lane >> 4;
  const int bn = blockIdx.x;                 // b*16 + n
  const int b = bn >> 4, nh = bn & 15;
  const char* Kg0 = (const char*)(Kb + (size_t)bn * TTT * 64);
  const char* Vg0 = (const char*)(Vt + (size_t)bn * 64 * TTT);

#pragma unroll
  for (int pass = 0; pass < 2; ++pass) {
    const int qtr = pass == 0 ? 15 - (int)blockIdx.y : (int)blockIdx.y;
    const int q0 = qtr * 64;

    const int qrow = q0 + wid * 16 + l15;
    const u16* qsrc = qkv + (size_t)(b * TTT + qrow) * 3072 + nh;
    bf16x8 aq[2];
#pragma unroll
    for (int ks = 0; ks < 2; ++ks) {
      short tmp[8];
#pragma unroll
      for (int j = 0; j < 8; ++j) tmp[j] = (short)qsrc[(ks * 32 + l4 * 8 + j) * 16];
      aq[ks] = *(bf16x8*)tmp;
    }

    float m_run[4], l_part[4];
    f32x4 o[4] = {};
#pragma unroll
    for (int r = 0; r < 4; ++r) { m_run[r] = -1e30f; l_part[r] = 0.f; }

    const int ntk = (qtr >> 1) + 1;
    for (int kt = 0; kt < ntk; ++kt) {
#pragma unroll
      for (int it = 0; it < 4; ++it) {
        int L = it * 4096 + tid * 16;
        int Ls = L ^ (((L >> 7) & 7) << 4);
        GLDS16(Kg0 + (size_t)kt * 16384 + Ls, (char*)Ks + L);
      }
#pragma unroll
      for (int it = 0; it < 4; ++it) {
        int L = it * 4096 + tid * 16;
        int Ls = L ^ (((L >> 8) & 7) << 4);
        int hrow = Ls >> 8, cb = Ls & 255;
        GLDS16(Vg0 + (size_t)hrow * 2048 + kt * 256 + cb, (char*)Vs + L);
      }
      __syncthreads();

      f32x4 sf[8];
#pragma unroll
      for (int cf = 0; cf < 8; ++cf) {
        f32x4 z = {};
#pragma unroll
        for (int ks = 0; ks < 2; ++ks) {
          int P = (cf * 16 + l15) * 128 + (ks * 32 + l4 * 8) * 2;
          bf16x8 kb = *(const bf16x8*)((const char*)Ks + (P ^ (((P >> 7) & 7) << 4)));
          z = __builtin_amdgcn_mfma_f32_16x16x32_bf16(aq[ks], kb, z, 0, 0, 0);
        }
        sf[cf] = z;
      }
      const bool lastkt = (kt == ntk - 1);
#pragma unroll
      for (int cf = 0; cf < 8; ++cf)
#pragma unroll
        for (int r = 0; r < 4; ++r) {
          float s = sf[cf][r] * 0.125f;
          if (lastkt) {
            int kg = kt * 128 + cf * 16 + l15;
            int qg = q0 + wid * 16 + l4 * 4 + r;
            if (kg > qg) s = -1e30f;
          }
          sf[cf][r] = s;
        }
      float fac[4];
#pragma unroll
      for (int r = 0; r < 4; ++r) {
        float tm = sf[0][r];
#pragma unroll
        for (int cf = 1; cf < 8; ++cf) tm = fmaxf(tm, sf[cf][r]);
#pragma unroll
        for (int off = 1; off < 16; off <<= 1) tm = fmaxf(tm, __shfl_xor(tm, off));
        float mnew = fmaxf(m_run[r], tm);
        fac[r] = __expf(m_run[r] - mnew);
        m_run[r] = mnew;
        float ps = 0.f;
#pragma unroll
        for (int cf = 0; cf < 8; ++cf) {
          float p = __expf(sf[cf][r] - mnew);
          sf[cf][r] = p;
          ps += p;
        }
        l_part[r] = l_part[r] * fac[r] + ps;
      }
#pragma unroll
      for (int cf = 0; cf < 8; ++cf)
#pragma unroll
        for (int r = 0; r < 4; ++r)
          Ps[wid][(l4 * 4 + r) * 136 + cf * 16 + l15] = f2bf(sf[cf][r]);
#pragma unroll
      for (int hf = 0; hf < 4; ++hf)
#pragma unroll
        for (int r = 0; r < 4; ++r) o[hf][r] *= fac[r];
      bf16x8 pa[4];
#pragma unroll
      for (int ks = 0; ks < 4; ++ks)
        pa[ks] = *(const bf16x8*)&Ps[wid][l15 * 136 + ks * 32 + l4 * 8];
#pragma unroll
      for (int hf = 0; hf < 4; ++hf) {
#pragma unroll
        for (int ks = 0; ks < 4; ++ks) {
          int P = (hf * 16 + l15) * 256 + (ks * 32 + l4 * 8) * 2;
          bf16x8 vb = *(const bf16x8*)((const char*)Vs + (P ^ (((P >> 8) & 7) << 4)));
          o[hf] = __builtin_amdgcn_mfma_f32_16x16x32_bf16(pa[ks], vb, o[hf], 0, 0, 0);
        }
      }
      __syncthreads();
    }
    float lsum[4];
#pragma unroll
    for (int r = 0; r < 4; ++r) {
      float s = l_part[r];
#pragma unroll
      for (int off = 1; off < 16; off <<= 1) s += __shfl_xor(s, off);
      lsum[r] = s;
    }
#pragma unroll
    for (int hf = 0; hf < 4; ++hf)
#pragma unroll
      for (int r = 0; r < 4; ++r) {
        float val = o[hf][r] / lsum[r];
        size_t row = (size_t)b * TTT + q0 + wid * 16 + l4 * 4 + r;
        attout[row * DD + nh * 64 + hf * 16 + l15] = f2bf(val);
      }
  }
}

// ---------------- lm head: out[b][v] = dot(xlnf[b], wte[v]) fp32 ----------------
__global__ __launch_bounds__(256) void k_head(const float* __restrict__ xlnf,
                                              const float* __restrict__ wte,
                                              float* __restrict__ out) {
  __shared__ float xs[2 * DD];
  int tid = threadIdx.x;
#pragma unroll
  for (int i = 0; i < 2; ++i)
    *(float4*)(xs + i * DD + tid * 4) = *(const float4*)(xlnf + i * DD + tid * 4);
  __syncthreads();
  int wid = tid >> 6, lane = tid & 63;
  for (int v = blockIdx.x * 4 + wid; v < VVV; v += gridDim.x * 4) {
    const float* wr = wte + (size_t)v * DD;
    float a0 = 0.f, a1 = 0.f;
#pragma unroll
    for (int j = 0; j < 4; ++j) {
      const float4 wv = *(const float4*)(wr + lane * 16 + j * 4);
      const float4 x0 = *(const float4*)(xs + lane * 16 + j * 4);
      const float4 x1 = *(const float4*)(xs + DD + lane * 16 + j * 4);
      a0 += wv.x * x0.x + wv.y * x0.y + wv.z * x0.z + wv.w * x0.w;
      a1 += wv.x * x1.x + wv.y * x1.y + wv.z * x1.z + wv.w * x1.w;
    }
#pragma unroll
    for (int off = 1; off < 64; off <<= 1) { a0 += __shfl_xor(a0, off); a1 += __shfl_xor(a1, off); }
    if (lane == 0) { out[v] = a0; out[VVV + v] = a1; }
  }
}

extern "C" void kernel_launch(void* const* d_in, const int* in_sizes, int n_in,
                              void* d_out, int out_size, void* d_ws, size_t ws_size,
                              hipStream_t stream) {
  const int* tokens    = (const int*)d_in[0];
  const float* wte     = (const float*)d_in[1];
  const float* wpe     = (const float*)d_in[2];
  const float* ln1_w   = (const float*)d_in[3];
  const float* ln1_b   = (const float*)d_in[4];
  const float* attn_w  = (const float*)d_in[5];
  const float* attn_b  = (const float*)d_in[6];
  const float* aproj_w = (const float*)d_in[7];
  const float* aproj_b = (const float*)d_in[8];
  const float* ln2_w   = (const float*)d_in[9];
  const float* ln2_b   = (const float*)d_in[10];
  const float* fc_w    = (const float*)d_in[11];
  const float* fc_b    = (const float*)d_in[12];
  const float* proj_w  = (const float*)d_in[13];
  const float* proj_b  = (const float*)d_in[14];
  const float* lnf_w   = (const float*)d_in[15];
  const float* lnf_b   = (const float*)d_in[16];

  char* ws = (char*)d_ws;
  float* x    = (float*)(ws);                    // 0..8 MiB
  u16* h      = (u16*)(ws + (8u << 20));         // 8..12
  u16* wt     = (u16*)(ws + (12u << 20));        // 12..36 (atw/apw/fcw/pjw)
  u16* qkv    = (u16*)(ws + (36u << 20));        // 36..48
  u16* Kb     = (u16*)(ws + (48u << 20));        // 48..52
  u16* Vt     = (u16*)(ws + (52u << 20));        // 52..56
  u16* attb   = (u16*)(ws + (56u << 20));        // 56..60
  u16* mlph   = (u16*)(ws + (36u << 20));        // 36..52 (aliases dead qkv/Kb)
  float* xlnf = (float*)(ws + (60u << 20));      // 60 MiB + 8 KB
  float* out  = (float*)d_out;

  u16* atw = wt;
  u16* apw = wt + 3145728;
  u16* fcw = wt + 4194304;
  u16* pjw = wt + 8388608;

  k_embed<<<MR, 256, 0, stream>>>(tokens, wte, wpe, x);

  for (int l = 0; l < 12; ++l) {
    k_wtrans_all<<<12288, 256, 0, stream>>>(attn_w + (size_t)l * DD * 3 * DD,
                                            aproj_w + (size_t)l * DD * DD,
                                            fc_w + (size_t)l * DD * FFF,
                                            proj_w + (size_t)l * FFF * DD, wt);
    k_ln<<<MR, 256, 0, stream>>>(x, ln1_w + l * DD, ln1_b + l * DD, h);
    k_gemm<0><<<dim3(16, 24, 1), 256, 0, stream>>>(h, atw, attn_b + (size_t)l * 3 * DD, qkv, nullptr, MR, 3072, 1024, 1024);
    k_repack<<<dim3(128, 2), 256, 0, stream>>>(qkv, Kb, Vt);
    k_attn<<<dim3(32, 8), 256, 0, stream>>>(qkv, Kb, Vt, attb);
    k_gemm<3><<<dim3(16, 8, 2), 256, 0, stream>>>(attb, apw, aproj_b + (size_t)l * DD, nullptr, x, MR, 1024, 1024, 512);
    k_ln<<<MR, 256, 0, stream>>>(x, ln2_w + l * DD, ln2_b + l * DD, h);
    k_gemm<2><<<dim3(16, 32, 1), 256, 0, stream>>>(h, fcw, fc_b + (size_t)l * FFF, mlph, nullptr, MR, 4096, 1024, 1024);
    k_gemm<3><<<dim3(16, 8, 4), 256, 0, stream>>>(mlph, pjw, proj_b + (size_t)l * DD, nullptr, x, MR, 1024, 4096, 1024);
  }
  k_lnf<<<2, 256, 0, stream>>>(x, lnf_w, lnf_b, xlnf);
  k_head<<<512, 256, 0, stream>>>(xlnf, wte, out);
}